// Round 2
// baseline (58594.385 us; speedup 1.0000x reference)
//
#include <hip/hip_runtime.h>
#include <hip/hip_cooperative_groups.h>
#include <math.h>

namespace cg = cooperative_groups;

#define B_ 64
#define S_ 512
#define I_ 300
#define H_ 512
#define G_ 2048   // 4*H
#define T_ 25
#define K_ 812    // I_ + H_

// ---------------- workspace layout (float elements) ----------------
static constexpr size_t SZ_XT   = (size_t)S_ * I_ * B_;        // 9,830,400
static constexpr size_t OFS_XT  = 0;
static constexpr size_t OFS_XRT = OFS_XT + SZ_XT;
static constexpr size_t SZ_WC   = (size_t)2 * G_ * K_;         // 3,325,952
static constexpr size_t OFS_WC  = OFS_XRT + SZ_XT;
static constexpr size_t OFS_H0  = OFS_WC + SZ_WC;
static constexpr size_t OFS_H1  = OFS_H0 + (size_t)2 * H_ * B_;
static constexpr size_t OFS_C   = OFS_H1 + (size_t)2 * H_ * B_; // unused now
static constexpr size_t OFS_YF  = OFS_C + (size_t)2 * H_ * B_;
static constexpr size_t SZ_Y    = (size_t)S_ * H_ * B_;        // 16,777,216
static constexpr size_t OFS_YB  = OFS_YF + SZ_Y;
static constexpr size_t SZ_L    = (size_t)B_ * S_ * T_;        // 819,200
static constexpr size_t OFS_L1  = OFS_YB + SZ_Y;
static constexpr size_t OFS_L2  = OFS_L1 + SZ_L;
static constexpr size_t OFS_LEN = OFS_L2 + SZ_L;   // int32[64]
static constexpr size_t OFS_LLH = OFS_LEN + 64;    // float[64]

// output layout (float elements in d_out)
static constexpr size_t OFF_LOGITS = 1;
static constexpr size_t OFF_TAGS   = 1 + SZ_L;
static constexpr size_t OFF_MASK   = OFF_TAGS + (size_t)B_ * S_;

// ---------------- small utility kernels ----------------
__global__ void k_lengths(const int* __restrict__ am, int* __restrict__ len) {
    int b = threadIdx.x;
    int sum = 0;
    for (int s = 0; s < S_; ++s) sum += am[b * S_ + s];
    len[b] = sum;
}

__global__ void k_zero(float* __restrict__ p, int n) {
    int idx = blockIdx.x * 256 + threadIdx.x;
    if (idx < n) p[idx] = 0.f;
}

// Weights repacked [dir][u(512)][gate(4)][k(812)] = [W_ih row | W_hh row]
// so each wave's scalar-load stream is one contiguous 13 KB row.
__global__ void k_prep_w2(const float* __restrict__ wihf, const float* __restrict__ whhf,
                          const float* __restrict__ wihb, const float* __restrict__ whhb,
                          float* __restrict__ wcomb) {
    size_t total = (size_t)2 * H_ * 4 * K_;
    for (size_t idx = (size_t)blockIdx.x * 256 + threadIdx.x; idx < total;
         idx += (size_t)gridDim.x * 256) {
        int dir = (int)(idx / ((size_t)H_ * 4 * K_));
        int r   = (int)(idx % ((size_t)H_ * 4 * K_));
        int u   = r / (4 * K_);
        int r2  = r % (4 * K_);
        int g   = r2 / K_;
        int k   = r2 % K_;
        int row = g * H_ + u;
        const float* wih = dir ? wihb : wihf;
        const float* whh = dir ? whhb : whhf;
        wcomb[idx] = (k < I_) ? wih[(size_t)row * I_ + k]
                              : whh[(size_t)row * H_ + (k - I_)];
    }
}

// Transpose x[b][s][i] -> x_t[s][i][b]; rev variant gathers per-batch reversed rows.
__global__ __launch_bounds__(256) void k_transpose(const float* __restrict__ x,
                                                   const int* __restrict__ len,
                                                   float* __restrict__ xt,
                                                   float* __restrict__ xrt) {
    __shared__ float tile[B_][153];
    int bid = blockIdx.x;
    int s = bid & 511;
    int isrev = bid >> 9;   // grid = 1024
    int tid = threadIdx.x;
    float* dst = (isrev ? xrt : xt) + (size_t)s * I_ * B_;
    for (int c = 0; c < 2; ++c) {
        int i0 = c * 150;
        for (int b2 = 0; b2 < B_; ++b2) {
            int src = s;
            if (isrev) { int L = len[b2]; src = (s < L) ? (L - 1 - s) : s; }
            for (int i = tid; i < 150; i += 256)
                tile[b2][i] = x[((size_t)b2 * S_ + src) * I_ + i0 + i];
        }
        __syncthreads();
        for (int idx = tid; idx < 150 * B_; idx += 256) {
            int i = idx >> 6;
            int b2 = idx & 63;
            dst[(size_t)(i0 + i) * B_ + b2] = tile[b2][i];
        }
        __syncthreads();
    }
}

// ---------------- persistent BiLSTM scan (cooperative) ----------------
// 256 blocks x 256 threads, 1 block/CU. dir = bid>>7, wave = unit, lane = batch.
// Weights: wave-uniform scalar loads (SGPR operand into v_fmac -> no LDS
// broadcast replication). Activations (x-row ++ h): staged into 64 KB LDS
// in 7 double-buffered 128-k chunks. c and own-h live in registers across
// all 512 steps; full h exchanged via global ping-pong + grid.sync().
__global__ __launch_bounds__(256) void k_lstm_persist(
    const float* __restrict__ xt, const float* __restrict__ xrt,
    const float* __restrict__ wc2,
    const float* __restrict__ bf, const float* __restrict__ bb,
    float* __restrict__ h0, float* __restrict__ h1,
    float* __restrict__ yf, float* __restrict__ ybr,
    const int* __restrict__ len) {
    __shared__ float hl[2][128 * 64];   // 64 KB exactly
    cg::grid_group grid = cg::this_grid();

    const int bid = blockIdx.x;
    const int dir = bid >> 7;
    const int ug  = bid & 127;
    const int tid = threadIdx.x;
    const int lane = tid & 63;
    const int wq = __builtin_amdgcn_readfirstlane(tid >> 6);  // force uniform
    const int u  = ug * 4 + wq;

    const float* __restrict__ wrow = wc2 + (((size_t)dir * H_ + u) * 4) * K_;
    const float* bias = dir ? bb : bf;
    const float b_i = bias[0 * H_ + u];
    const float b_f = bias[1 * H_ + u];
    const float b_g = bias[2 * H_ + u];
    const float b_o = bias[3 * H_ + u];
    const int Lb = len[lane];
    const float* __restrict__ xbase = dir ? xrt : xt;
    float* __restrict__ ybase = dir ? ybr : yf;

    float c_reg = 0.f, h_reg = 0.f;

    for (int s = 0; s < S_; ++s) {
        const float* __restrict__ hin =
            ((s & 1) ? h1 : h0) + (size_t)dir * H_ * B_;
        float* __restrict__ hout =
            ((s & 1) ? h0 : h1) + (size_t)dir * H_ * B_;
        const float* __restrict__ xrow = xbase + (size_t)s * I_ * B_;

        // stage chunk 0 (k = 0..127, pure x) into buf0
        {
#pragma unroll
            for (int j = 0; j < 8; ++j) {
                int f = tid + j * 256;        // f < 2048
                int k = f >> 4;
                int b4 = (f & 15) << 2;
                ((float4*)hl[0])[f] =
                    *(const float4*)(xrow + ((size_t)k << 6) + b4);
            }
        }
        __syncthreads();

        float ai = b_i, af = b_f, ag = b_g, ao = b_o;
        for (int q = 0; q < 7; ++q) {
            const int k0 = q << 7;
            const int kn = (q == 6) ? 44 : 128;
            // prefetch next chunk into registers (overlaps compute)
            float4 r[8];
            int fmax_n = 0;
            if (q < 6) {
                const int k0n = (q + 1) << 7;
                fmax_n = ((q == 5) ? 44 : 128) << 4;
#pragma unroll
                for (int j = 0; j < 8; ++j) {
                    int f = tid + j * 256;
                    if (f < fmax_n) {
                        int k = k0n + (f >> 4);
                        int b4 = (f & 15) << 2;
                        const float* src = (k < I_)
                            ? (xrow + ((size_t)k << 6) + b4)
                            : (hin + ((size_t)(k - I_) << 6) + b4);
                        r[j] = *(const float4*)src;
                    }
                }
            }
            // compute chunk q: acts from LDS (distinct-lane b32, conflict-free),
            // weights wave-uniform -> scalar loads.
            const float* __restrict__ wl = wrow + k0;
            const float* al = &hl[q & 1][lane];
            for (int kk = 0; kk < kn; kk += 4) {
                float a0 = al[(kk + 0) << 6];
                float a1 = al[(kk + 1) << 6];
                float a2 = al[(kk + 2) << 6];
                float a3 = al[(kk + 3) << 6];
                ai += a0 * wl[0 * K_ + kk] + a1 * wl[0 * K_ + kk + 1] +
                      a2 * wl[0 * K_ + kk + 2] + a3 * wl[0 * K_ + kk + 3];
                af += a0 * wl[1 * K_ + kk] + a1 * wl[1 * K_ + kk + 1] +
                      a2 * wl[1 * K_ + kk + 2] + a3 * wl[1 * K_ + kk + 3];
                ag += a0 * wl[2 * K_ + kk] + a1 * wl[2 * K_ + kk + 1] +
                      a2 * wl[2 * K_ + kk + 2] + a3 * wl[2 * K_ + kk + 3];
                ao += a0 * wl[3 * K_ + kk] + a1 * wl[3 * K_ + kk + 1] +
                      a2 * wl[3 * K_ + kk + 2] + a3 * wl[3 * K_ + kk + 3];
            }
            if (q < 6) {
                float4* d = (float4*)hl[(q + 1) & 1];
#pragma unroll
                for (int j = 0; j < 8; ++j) {
                    int f = tid + j * 256;
                    if (f < fmax_n) d[f] = r[j];
                }
            }
            __syncthreads();
        }

        float ii = 1.f / (1.f + expf(-ai));
        float f2 = 1.f / (1.f + expf(-af));
        float gg = tanhf(ag);
        float oo = 1.f / (1.f + expf(-ao));
        float cn = f2 * c_reg + ii * gg;
        float hn = oo * tanhf(cn);
        bool valid = (s < Lb);
        if (valid) { c_reg = cn; h_reg = hn; }
        hout[((size_t)u << 6) + lane] = h_reg;
        ybase[(((size_t)s * H_ + u) << 6) + lane] = valid ? hn : 0.f;

        __threadfence();
        grid.sync();
    }
}

// ---------------- logits / CRF epilogue (unchanged from round 1) ----------------
__global__ __launch_bounds__(256) void k_logits(const float* __restrict__ yf,
                                                const float* __restrict__ ybr,
                                                const float* __restrict__ wc,
                                                const float* __restrict__ bcv,
                                                float* __restrict__ L1,
                                                float* __restrict__ L2p) {
    __shared__ float smem[T_ * H_];
    int part = blockIdx.x >> 9;
    int s = blockIdx.x & 511;
    int tid = threadIdx.x;
    const float* y = part ? ybr : yf;
    float* Ldst = part ? L2p : L1;
    for (int idx = tid; idx < T_ * H_; idx += 256) {
        int t = idx >> 9;
        int h = idx & 511;
        smem[idx] = wc[(size_t)t * 1024 + part * 512 + h];
    }
    __syncthreads();
    int q = tid >> 6, b = tid & 63;
    float acc[T_];
#pragma unroll
    for (int t = 0; t < T_; ++t) acc[t] = 0.f;
    const float* yrow = y + (size_t)s * H_ * B_ + b;
    for (int h = q * 128; h < q * 128 + 128; ++h) {
        float a = yrow[(size_t)h * B_];
#pragma unroll
        for (int t = 0; t < T_; ++t) acc[t] += a * smem[t * H_ + h];
    }
    __syncthreads();
    float* pl = smem;
#pragma unroll
    for (int t = 0; t < T_; ++t) pl[(q * 64 + b) * 26 + t] = acc[t];
    __syncthreads();
    for (int idx = tid; idx < B_ * T_; idx += 256) {
        int bb2 = idx / T_;
        int t = idx - bb2 * T_;
        float v = pl[(0 * 64 + bb2) * 26 + t] + pl[(1 * 64 + bb2) * 26 + t] +
                  pl[(2 * 64 + bb2) * 26 + t] + pl[(3 * 64 + bb2) * 26 + t];
        if (!part) v += bcv[t];
        Ldst[((size_t)bb2 * S_ + s) * T_ + t] = v;
    }
}

__global__ void k_combine(const float* __restrict__ L1, const float* __restrict__ L2p,
                          const int* __restrict__ len, float* __restrict__ outlog) {
    int id = blockIdx.x * 256 + threadIdx.x;  // 32768 = B*S
    int b = id >> 9;
    int s = id & 511;
    int L = len[b];
    int sr = (s < L) ? (L - 1 - s) : s;
    const float* p1 = L1 + ((size_t)b * S_ + s) * T_;
    const float* p2 = L2p + ((size_t)b * S_ + sr) * T_;
    float* o = outlog + ((size_t)b * S_ + s) * T_;
#pragma unroll
    for (int t = 0; t < T_; ++t) o[t] = p1[t] + p2[t];
}

__global__ __launch_bounds__(64) void k_crf_nll(const float* __restrict__ em,
                                                const int* __restrict__ labels,
                                                const int* __restrict__ len,
                                                const float* __restrict__ cs,
                                                const float* __restrict__ ce,
                                                const float* __restrict__ ctr,
                                                float* __restrict__ llh) {
    int b = blockIdx.x, tid = threadIdx.x;
    __shared__ float tr[T_ * T_];
    __shared__ float sa[T_], sb[T_];
    for (int idx = tid; idx < T_ * T_; idx += 64) tr[idx] = ctr[idx];
    const float* e = em + (size_t)b * S_ * T_;
    int L = len[b];
    if (tid < T_) sa[tid] = cs[tid] + e[tid];
    __syncthreads();
    float* cur = sa;
    float* nx = sb;
    for (int t = 1; t < L; ++t) {
        if (tid < T_) {
            float m = -1e30f;
            for (int i = 0; i < T_; ++i) m = fmaxf(m, cur[i] + tr[i * T_ + tid]);
            float ssum = 0.f;
            for (int i = 0; i < T_; ++i) ssum += expf(cur[i] + tr[i * T_ + tid] - m);
            nx[tid] = m + logf(ssum) + e[(size_t)t * T_ + tid];
        }
        __syncthreads();
        float* tmp = cur; cur = nx; nx = tmp;
    }
    float part = 0.f;
    for (int t = tid; t < S_; t += 64) {
        if (t >= 1 && t < L) {
            int lp = labels[b * S_ + t - 1];
            int lc = labels[b * S_ + t];
            part += tr[lp * T_ + lc] + e[(size_t)t * T_ + lc];
        }
    }
    for (int off = 32; off; off >>= 1) part += __shfl_down(part, off, 64);
    if (tid == 0) {
        float m = -1e30f;
        for (int j = 0; j < T_; ++j) m = fmaxf(m, cur[j] + ce[j]);
        float ssum = 0.f;
        for (int j = 0; j < T_; ++j) ssum += expf(cur[j] + ce[j] - m);
        float denom = m + logf(ssum);
        int l0 = labels[b * S_];
        int lL = labels[b * S_ + L - 1];
        float num = cs[l0] + e[l0] + part + ce[lL];
        llh[b] = num - denom;
    }
}

__global__ void k_loss(const float* __restrict__ llh, const int* __restrict__ len,
                       float* __restrict__ out0) {
    int tid = threadIdx.x;
    float v = llh[tid];
    float n = (float)len[tid];
    for (int off = 32; off; off >>= 1) {
        v += __shfl_down(v, off, 64);
        n += __shfl_down(n, off, 64);
    }
    if (tid == 0) out0[0] = -(v / n);
}

__global__ __launch_bounds__(64) void k_viterbi(const float* __restrict__ em,
                                                const int* __restrict__ len,
                                                const float* __restrict__ cs,
                                                const float* __restrict__ ce,
                                                const float* __restrict__ ctr,
                                                float* __restrict__ otags,
                                                float* __restrict__ omask) {
    int b = blockIdx.x, tid = threadIdx.x;
    __shared__ float tr[T_ * T_];
    __shared__ float sa[T_], sb[T_];
    __shared__ unsigned char hist[(S_ - 1) * T_];
    __shared__ unsigned char tg[S_];
    for (int idx = tid; idx < T_ * T_; idx += 64) tr[idx] = ctr[idx];
    const float* e = em + (size_t)b * S_ * T_;
    int L = len[b];
    if (tid < T_) sa[tid] = cs[tid] + e[tid];
    __syncthreads();
    float* cur = sa;
    float* nx = sb;
    for (int t = 1; t < L; ++t) {
        if (tid < T_) {
            float best = -1e30f;
            int bi = 0;
            for (int i = 0; i < T_; ++i) {
                float v = cur[i] + tr[i * T_ + tid];
                if (v > best) { best = v; bi = i; }
            }
            nx[tid] = best + e[(size_t)t * T_ + tid];
            hist[(t - 1) * T_ + tid] = (unsigned char)bi;
        }
        __syncthreads();
        float* tmp = cur; cur = nx; nx = tmp;
    }
    if (tid == 0) {
        float best = -1e30f;
        int bt = 0;
        for (int j = 0; j < T_; ++j) {
            float v = cur[j] + ce[j];
            if (v > best) { best = v; bt = j; }
        }
        tg[S_ - 1] = (unsigned char)bt;
        for (int t = S_ - 2; t >= 0; --t) {
            if (t + 1 < L) bt = hist[t * T_ + bt];
            tg[t] = (unsigned char)bt;
        }
    }
    __syncthreads();
    for (int idx = tid; idx < S_; idx += 64) {
        otags[(size_t)b * S_ + idx] = (float)tg[idx];
        omask[(size_t)b * S_ + idx] = (idx < L) ? 1.f : 0.f;
    }
}

// ---------------- host launch ----------------
extern "C" void kernel_launch(void* const* d_in, const int* in_sizes, int n_in,
                              void* d_out, int out_size, void* d_ws, size_t ws_size,
                              hipStream_t stream) {
    const float* x    = (const float*)d_in[0];
    const float* wihf = (const float*)d_in[1];
    const float* whhf = (const float*)d_in[2];
    const float* bf   = (const float*)d_in[3];
    const float* wihb = (const float*)d_in[4];
    const float* whhb = (const float*)d_in[5];
    const float* bb   = (const float*)d_in[6];
    const float* wc   = (const float*)d_in[7];
    const float* bc   = (const float*)d_in[8];
    const float* cs   = (const float*)d_in[9];
    const float* ce   = (const float*)d_in[10];
    const float* ctr  = (const float*)d_in[11];
    const int* am     = (const int*)d_in[12];
    const int* labels = (const int*)d_in[13];

    float* ws   = (float*)d_ws;
    float* xt   = ws + OFS_XT;
    float* xrt  = ws + OFS_XRT;
    float* wcmb = ws + OFS_WC;
    float* h0   = ws + OFS_H0;
    float* h1   = ws + OFS_H1;
    float* yf   = ws + OFS_YF;
    float* ybr  = ws + OFS_YB;
    float* L1p  = ws + OFS_L1;
    float* L2p  = ws + OFS_L2;
    int*   lenp = (int*)(ws + OFS_LEN);
    float* llhp = ws + OFS_LLH;
    float* out  = (float*)d_out;

    k_lengths<<<1, 64, 0, stream>>>(am, lenp);
    k_prep_w2<<<2048, 256, 0, stream>>>(wihf, whhf, wihb, whhb, wcmb);
    k_zero<<<512, 256, 0, stream>>>(h0, 2 * 2 * H_ * B_);  // h0 and h1
    k_transpose<<<1024, 256, 0, stream>>>(x, lenp, xt, xrt);

    {
        void* kargs[] = {
            (void*)&xt, (void*)&xrt, (void*)&wcmb,
            (void*)&bf, (void*)&bb,
            (void*)&h0, (void*)&h1,
            (void*)&yf, (void*)&ybr,
            (void*)&lenp
        };
        hipLaunchCooperativeKernel((const void*)k_lstm_persist,
                                   dim3(256), dim3(256), kargs, 0, stream);
    }

    k_logits<<<1024, 256, 0, stream>>>(yf, ybr, wc, bc, L1p, L2p);
    k_combine<<<128, 256, 0, stream>>>(L1p, L2p, lenp, out + OFF_LOGITS);
    k_crf_nll<<<64, 64, 0, stream>>>(out + OFF_LOGITS, labels, lenp, cs, ce, ctr, llhp);
    k_loss<<<1, 64, 0, stream>>>(llhp, lenp, out);
    k_viterbi<<<64, 64, 0, stream>>>(out + OFF_LOGITS, lenp, cs, ce, ctr,
                                     out + OFF_TAGS, out + OFF_MASK);
}

// Round 3
// 21992.702 us; speedup vs baseline: 2.6643x; 2.6643x over previous
//
#include <hip/hip_runtime.h>
#include <math.h>

#define B_ 64
#define S_ 512
#define I_ 300
#define H_ 512
#define G_ 2048   // 4*H
#define T_ 25
#define K_ 812    // I_ + H_

// ---------------- workspace layout (float elements) ----------------
static constexpr size_t SZ_XT   = (size_t)S_ * B_ * I_;        // 9,830,400
static constexpr size_t OFS_XT  = 0;                            // xt2 [s][b][300]
static constexpr size_t OFS_XRT = OFS_XT + SZ_XT;               // xrt2 [s][b][300]
static constexpr size_t SZ_WC   = (size_t)2 * G_ * K_;          // 3,325,952
static constexpr size_t OFS_WC  = OFS_XRT + SZ_XT;              // [dir][u][g][k]
static constexpr size_t OFS_H0  = OFS_WC + SZ_WC;               // [dir][u][b]
static constexpr size_t OFS_H1  = OFS_H0 + (size_t)2 * H_ * B_;
static constexpr size_t OFS_C   = OFS_H1 + (size_t)2 * H_ * B_;
static constexpr size_t OFS_YF  = OFS_C + (size_t)2 * H_ * B_;  // [s][h][b]
static constexpr size_t SZ_Y    = (size_t)S_ * H_ * B_;         // 16,777,216
static constexpr size_t OFS_YB  = OFS_YF + SZ_Y;
static constexpr size_t SZ_L    = (size_t)B_ * S_ * T_;         // 819,200
static constexpr size_t OFS_L1  = OFS_YB + SZ_Y;
static constexpr size_t OFS_L2  = OFS_L1 + SZ_L;
static constexpr size_t OFS_LEN = OFS_L2 + SZ_L;   // int32[64]
static constexpr size_t OFS_LLH = OFS_LEN + 64;    // float[64]

// output layout (float elements in d_out)
static constexpr size_t OFF_LOGITS = 1;
static constexpr size_t OFF_TAGS   = 1 + SZ_L;
static constexpr size_t OFF_MASK   = OFF_TAGS + (size_t)B_ * S_;

// ---------------- small utility kernels ----------------
__global__ void k_lengths(const int* __restrict__ am, int* __restrict__ len) {
    int b = threadIdx.x;
    int sum = 0;
    for (int s = 0; s < S_; ++s) sum += am[b * S_ + s];
    len[b] = sum;
}

__global__ void k_zero(float* __restrict__ p, int n) {
    int idx = blockIdx.x * 256 + threadIdx.x;
    if (idx < n) p[idx] = 0.f;
}

// Weights [dir][u(512)][gate(4)][k(812)] = [W_ih row | W_hh row]
// Each wave's weight stream is one contiguous 13 KB row -> s_load friendly.
__global__ void k_prep_w2(const float* __restrict__ wihf, const float* __restrict__ whhf,
                          const float* __restrict__ wihb, const float* __restrict__ whhb,
                          float* __restrict__ wcomb) {
    size_t total = (size_t)2 * H_ * 4 * K_;
    for (size_t idx = (size_t)blockIdx.x * 256 + threadIdx.x; idx < total;
         idx += (size_t)gridDim.x * 256) {
        int dir = (int)(idx / ((size_t)H_ * 4 * K_));
        int r   = (int)(idx % ((size_t)H_ * 4 * K_));
        int u   = r / (4 * K_);
        int r2  = r % (4 * K_);
        int g   = r2 / K_;
        int k   = r2 % K_;
        int row = g * H_ + u;
        const float* wih = dir ? wihb : wihf;
        const float* whh = dir ? whhb : whhf;
        wcomb[idx] = (k < I_) ? wih[(size_t)row * I_ + k]
                              : whh[(size_t)row * H_ + (k - I_)];
    }
}

// x[b][s][i] -> xt2[s][b][i]  (batch-major rows); rev variant gathers reversed.
// Flat dw index makes writes perfectly coalesced; reads are row-contiguous runs.
__global__ __launch_bounds__(256) void k_xpose2(const float* __restrict__ x,
                                                const int* __restrict__ len,
                                                float* __restrict__ xt2,
                                                float* __restrict__ xrt2) {
    __shared__ int lsrc[B_];
    int bid = blockIdx.x;          // 1024: s = bid&511, rev = bid>>9
    int s = bid & 511, isrev = bid >> 9;
    int tid = threadIdx.x;
    if (tid < B_) {
        int src = s;
        if (isrev) { int L = len[tid]; src = (s < L) ? (L - 1 - s) : s; }
        lsrc[tid] = src;
    }
    __syncthreads();
    float* dst = (isrev ? xrt2 : xt2) + (size_t)s * B_ * I_;
    for (int dw = tid; dw < B_ * I_; dw += 256) {
        int b = dw / I_;
        int k = dw - b * I_;
        dst[dw] = x[((size_t)b * S_ + lsrc[b]) * I_ + k];
    }
}

// ---------------- one BiLSTM time step ----------------
// 256 blocks x 256 threads. dir = bid>>7; wave w owns unit u = (bid&127)*4 + w;
// lane = batch. Weights: wave-uniform scalar loads (SGPR operand -> no LDS).
// h acts: staged to LDS in [b][k] layout with XOR-swizzled 16B granules, read
// as per-lane-distinct ds_read_b128 (1 KB distinct/instr). x acts: direct
// global [s][b][300] dwordx4 (L1-cached, concurrent with LDS pipe).
__global__ __launch_bounds__(256) void k_step(
    int s,
    const float* __restrict__ wc2,
    const float* __restrict__ xt2, const float* __restrict__ xrt2,
    const float* __restrict__ hin, float* __restrict__ hout,
    float* __restrict__ cst,
    float* __restrict__ yf, float* __restrict__ ybr,
    const float* __restrict__ bf, const float* __restrict__ bb,
    const int* __restrict__ len) {
    __shared__ float hl[B_ * 256];   // 64 KB: [b][256 dwords], swizzled granules
    const int bid = blockIdx.x;
    const int dir = bid >> 7;
    const int ug  = bid & 127;
    const int tid = threadIdx.x;
    const int lane = tid & 63;
    const int wq0 = tid >> 6;
    const int swz = lane & 31;

    const float* __restrict__ hsrc = hin + (size_t)dir * (H_ * B_);

    const int wq = __builtin_amdgcn_readfirstlane(wq0);
    const int u  = (ug << 2) + wq;
    const float* __restrict__ w0 = wc2 + (((size_t)dir * H_ + u) * 4) * K_;
    const float* __restrict__ w1 = w0 + K_;
    const float* __restrict__ w2 = w1 + K_;
    const float* __restrict__ w3 = w2 + K_;
    const float* bias = dir ? bb : bf;
    float ai = bias[u], af2 = bias[H_ + u], ag = bias[2 * H_ + u], ao = bias[3 * H_ + u];

    // ---- stage h chunk 0 (k 0..255) ----
    for (int gs = wq0; gs < 64; gs += 4) {
        int k = gs << 2;
        float4 v;
        v.x = hsrc[(k + 0) * B_ + lane];
        v.y = hsrc[(k + 1) * B_ + lane];
        v.z = hsrc[(k + 2) * B_ + lane];
        v.w = hsrc[(k + 3) * B_ + lane];
        *(float4*)&hl[(lane << 8) + ((gs ^ swz) << 2)] = v;
    }
    __syncthreads();

    // ---- x part (k 0..299), global direct ----
    const float* __restrict__ xrow =
        (dir ? xrt2 : xt2) + ((size_t)s * B_ + lane) * I_;
#pragma unroll 5
    for (int k4 = 0; k4 < I_ / 4; ++k4) {
        float4 a = *(const float4*)(xrow + (k4 << 2));
        int k = k4 << 2;
        ai  += a.x * w0[k] + a.y * w0[k + 1] + a.z * w0[k + 2] + a.w * w0[k + 3];
        af2 += a.x * w1[k] + a.y * w1[k + 1] + a.z * w1[k + 2] + a.w * w1[k + 3];
        ag  += a.x * w2[k] + a.y * w2[k + 1] + a.z * w2[k + 2] + a.w * w2[k + 3];
        ao  += a.x * w3[k] + a.y * w3[k + 1] + a.z * w3[k + 2] + a.w * w3[k + 3];
    }

    // ---- h part chunk 0 (k 300..555 of weight row) ----
    const float* hb = &hl[lane << 8];
#pragma unroll 4
    for (int g = 0; g < 64; ++g) {
        float4 a = *(const float4*)(hb + ((g ^ swz) << 2));
        int k = I_ + (g << 2);
        ai  += a.x * w0[k] + a.y * w0[k + 1] + a.z * w0[k + 2] + a.w * w0[k + 3];
        af2 += a.x * w1[k] + a.y * w1[k + 1] + a.z * w1[k + 2] + a.w * w1[k + 3];
        ag  += a.x * w2[k] + a.y * w2[k + 1] + a.z * w2[k + 2] + a.w * w2[k + 3];
        ao  += a.x * w3[k] + a.y * w3[k + 1] + a.z * w3[k + 2] + a.w * w3[k + 3];
    }
    __syncthreads();

    // ---- stage h chunk 1 (k 256..511) ----
    for (int gs = wq0; gs < 64; gs += 4) {
        int k = 256 + (gs << 2);
        float4 v;
        v.x = hsrc[(k + 0) * B_ + lane];
        v.y = hsrc[(k + 1) * B_ + lane];
        v.z = hsrc[(k + 2) * B_ + lane];
        v.w = hsrc[(k + 3) * B_ + lane];
        *(float4*)&hl[(lane << 8) + ((gs ^ swz) << 2)] = v;
    }
    __syncthreads();

    // ---- h part chunk 1 (k 556..811 of weight row) ----
#pragma unroll 4
    for (int g = 0; g < 64; ++g) {
        float4 a = *(const float4*)(hb + ((g ^ swz) << 2));
        int k = I_ + 256 + (g << 2);
        ai  += a.x * w0[k] + a.y * w0[k + 1] + a.z * w0[k + 2] + a.w * w0[k + 3];
        af2 += a.x * w1[k] + a.y * w1[k + 1] + a.z * w1[k + 2] + a.w * w1[k + 3];
        ag  += a.x * w2[k] + a.y * w2[k + 1] + a.z * w2[k + 2] + a.w * w2[k + 3];
        ao  += a.x * w3[k] + a.y * w3[k + 1] + a.z * w3[k + 2] + a.w * w3[k + 3];
    }

    // ---- gate nonlinearity + state update ----
    int L = len[lane];
    bool valid = (s < L);
    size_t idx = ((size_t)dir * H_ + u) * B_ + lane;
    float hp = hsrc[(u << 6) + lane];
    float cp = cst[idx];
    float ii = 1.f / (1.f + expf(-ai));
    float ff = 1.f / (1.f + expf(-af2));
    float gg = tanhf(ag);
    float oo = 1.f / (1.f + expf(-ao));
    float cn = ff * cp + ii * gg;
    float hn = oo * tanhf(cn);
    hout[idx] = valid ? hn : hp;
    if (valid) cst[idx] = cn;
    (dir ? ybr : yf)[(((size_t)s * H_ + u) << 6) + lane] = valid ? hn : 0.f;
}

// ---------------- logits / CRF epilogue ----------------
__global__ __launch_bounds__(256) void k_logits(const float* __restrict__ yf,
                                                const float* __restrict__ ybr,
                                                const float* __restrict__ wc,
                                                const float* __restrict__ bcv,
                                                float* __restrict__ L1,
                                                float* __restrict__ L2p) {
    __shared__ float smem[T_ * H_];
    int part = blockIdx.x >> 9;
    int s = blockIdx.x & 511;
    int tid = threadIdx.x;
    const float* y = part ? ybr : yf;
    float* Ldst = part ? L2p : L1;
    for (int idx = tid; idx < T_ * H_; idx += 256) {
        int t = idx >> 9;
        int h = idx & 511;
        smem[idx] = wc[(size_t)t * 1024 + part * 512 + h];
    }
    __syncthreads();
    int q = tid >> 6, b = tid & 63;
    float acc[T_];
#pragma unroll
    for (int t = 0; t < T_; ++t) acc[t] = 0.f;
    const float* yrow = y + (size_t)s * H_ * B_ + b;
    for (int h = q * 128; h < q * 128 + 128; ++h) {
        float a = yrow[(size_t)h * B_];
#pragma unroll
        for (int t = 0; t < T_; ++t) acc[t] += a * smem[t * H_ + h];
    }
    __syncthreads();
    float* pl = smem;
#pragma unroll
    for (int t = 0; t < T_; ++t) pl[(q * 64 + b) * 26 + t] = acc[t];
    __syncthreads();
    for (int idx = tid; idx < B_ * T_; idx += 256) {
        int bb2 = idx / T_;
        int t = idx - bb2 * T_;
        float v = pl[(0 * 64 + bb2) * 26 + t] + pl[(1 * 64 + bb2) * 26 + t] +
                  pl[(2 * 64 + bb2) * 26 + t] + pl[(3 * 64 + bb2) * 26 + t];
        if (!part) v += bcv[t];
        Ldst[((size_t)bb2 * S_ + s) * T_ + t] = v;
    }
}

__global__ void k_combine(const float* __restrict__ L1, const float* __restrict__ L2p,
                          const int* __restrict__ len, float* __restrict__ outlog) {
    int id = blockIdx.x * 256 + threadIdx.x;  // 32768 = B*S
    int b = id >> 9;
    int s = id & 511;
    int L = len[b];
    int sr = (s < L) ? (L - 1 - s) : s;
    const float* p1 = L1 + ((size_t)b * S_ + s) * T_;
    const float* p2 = L2p + ((size_t)b * S_ + sr) * T_;
    float* o = outlog + ((size_t)b * S_ + s) * T_;
#pragma unroll
    for (int t = 0; t < T_; ++t) o[t] = p1[t] + p2[t];
}

__global__ __launch_bounds__(64) void k_crf_nll(const float* __restrict__ em,
                                                const int* __restrict__ labels,
                                                const int* __restrict__ len,
                                                const float* __restrict__ cs,
                                                const float* __restrict__ ce,
                                                const float* __restrict__ ctr,
                                                float* __restrict__ llh) {
    int b = blockIdx.x, tid = threadIdx.x;
    __shared__ float tr[T_ * T_];
    __shared__ float sa[T_], sb[T_];
    for (int idx = tid; idx < T_ * T_; idx += 64) tr[idx] = ctr[idx];
    const float* e = em + (size_t)b * S_ * T_;
    int L = len[b];
    if (tid < T_) sa[tid] = cs[tid] + e[tid];
    __syncthreads();
    float* cur = sa;
    float* nx = sb;
    for (int t = 1; t < L; ++t) {
        if (tid < T_) {
            float m = -1e30f;
            for (int i = 0; i < T_; ++i) m = fmaxf(m, cur[i] + tr[i * T_ + tid]);
            float ssum = 0.f;
            for (int i = 0; i < T_; ++i) ssum += expf(cur[i] + tr[i * T_ + tid] - m);
            nx[tid] = m + logf(ssum) + e[(size_t)t * T_ + tid];
        }
        __syncthreads();
        float* tmp = cur; cur = nx; nx = tmp;
    }
    float part = 0.f;
    for (int t = tid; t < S_; t += 64) {
        if (t >= 1 && t < L) {
            int lp = labels[b * S_ + t - 1];
            int lc = labels[b * S_ + t];
            part += tr[lp * T_ + lc] + e[(size_t)t * T_ + lc];
        }
    }
    for (int off = 32; off; off >>= 1) part += __shfl_down(part, off, 64);
    if (tid == 0) {
        float m = -1e30f;
        for (int j = 0; j < T_; ++j) m = fmaxf(m, cur[j] + ce[j]);
        float ssum = 0.f;
        for (int j = 0; j < T_; ++j) ssum += expf(cur[j] + ce[j] - m);
        float denom = m + logf(ssum);
        int l0 = labels[b * S_];
        int lL = labels[b * S_ + L - 1];
        float num = cs[l0] + e[l0] + part + ce[lL];
        llh[b] = num - denom;
    }
}

__global__ void k_loss(const float* __restrict__ llh, const int* __restrict__ len,
                       float* __restrict__ out0) {
    int tid = threadIdx.x;
    float v = llh[tid];
    float n = (float)len[tid];
    for (int off = 32; off; off >>= 1) {
        v += __shfl_down(v, off, 64);
        n += __shfl_down(n, off, 64);
    }
    if (tid == 0) out0[0] = -(v / n);
}

__global__ __launch_bounds__(64) void k_viterbi(const float* __restrict__ em,
                                                const int* __restrict__ len,
                                                const float* __restrict__ cs,
                                                const float* __restrict__ ce,
                                                const float* __restrict__ ctr,
                                                float* __restrict__ otags,
                                                float* __restrict__ omask) {
    int b = blockIdx.x, tid = threadIdx.x;
    __shared__ float tr[T_ * T_];
    __shared__ float sa[T_], sb[T_];
    __shared__ unsigned char hist[(S_ - 1) * T_];
    __shared__ unsigned char tg[S_];
    for (int idx = tid; idx < T_ * T_; idx += 64) tr[idx] = ctr[idx];
    const float* e = em + (size_t)b * S_ * T_;
    int L = len[b];
    if (tid < T_) sa[tid] = cs[tid] + e[tid];
    __syncthreads();
    float* cur = sa;
    float* nx = sb;
    for (int t = 1; t < L; ++t) {
        if (tid < T_) {
            float best = -1e30f;
            int bi = 0;
            for (int i = 0; i < T_; ++i) {
                float v = cur[i] + tr[i * T_ + tid];
                if (v > best) { best = v; bi = i; }
            }
            nx[tid] = best + e[(size_t)t * T_ + tid];
            hist[(t - 1) * T_ + tid] = (unsigned char)bi;
        }
        __syncthreads();
        float* tmp = cur; cur = nx; nx = tmp;
    }
    if (tid == 0) {
        float best = -1e30f;
        int bt = 0;
        for (int j = 0; j < T_; ++j) {
            float v = cur[j] + ce[j];
            if (v > best) { best = v; bt = j; }
        }
        tg[S_ - 1] = (unsigned char)bt;
        for (int t = S_ - 2; t >= 0; --t) {
            if (t + 1 < L) bt = hist[t * T_ + bt];
            tg[t] = (unsigned char)bt;
        }
    }
    __syncthreads();
    for (int idx = tid; idx < S_; idx += 64) {
        otags[(size_t)b * S_ + idx] = (float)tg[idx];
        omask[(size_t)b * S_ + idx] = (idx < L) ? 1.f : 0.f;
    }
}

// ---------------- host launch ----------------
extern "C" void kernel_launch(void* const* d_in, const int* in_sizes, int n_in,
                              void* d_out, int out_size, void* d_ws, size_t ws_size,
                              hipStream_t stream) {
    const float* x    = (const float*)d_in[0];
    const float* wihf = (const float*)d_in[1];
    const float* whhf = (const float*)d_in[2];
    const float* bf   = (const float*)d_in[3];
    const float* wihb = (const float*)d_in[4];
    const float* whhb = (const float*)d_in[5];
    const float* bb   = (const float*)d_in[6];
    const float* wc   = (const float*)d_in[7];
    const float* bc   = (const float*)d_in[8];
    const float* cs   = (const float*)d_in[9];
    const float* ce   = (const float*)d_in[10];
    const float* ctr  = (const float*)d_in[11];
    const int* am     = (const int*)d_in[12];
    const int* labels = (const int*)d_in[13];

    float* ws   = (float*)d_ws;
    float* xt2  = ws + OFS_XT;
    float* xrt2 = ws + OFS_XRT;
    float* wcmb = ws + OFS_WC;
    float* h0   = ws + OFS_H0;
    float* h1   = ws + OFS_H1;
    float* cst  = ws + OFS_C;
    float* yf   = ws + OFS_YF;
    float* ybr  = ws + OFS_YB;
    float* L1p  = ws + OFS_L1;
    float* L2p  = ws + OFS_L2;
    int*   lenp = (int*)(ws + OFS_LEN);
    float* llhp = ws + OFS_LLH;
    float* out  = (float*)d_out;

    k_lengths<<<1, 64, 0, stream>>>(am, lenp);
    k_prep_w2<<<2048, 256, 0, stream>>>(wihf, whhf, wihb, whhb, wcmb);
    k_zero<<<768, 256, 0, stream>>>(h0, 3 * 2 * H_ * B_);  // h0, h1, c contiguous
    k_xpose2<<<1024, 256, 0, stream>>>(x, lenp, xt2, xrt2);

    for (int s = 0; s < S_; ++s) {
        const float* hin = (s & 1) ? h1 : h0;
        float* hout      = (s & 1) ? h0 : h1;
        k_step<<<256, 256, 0, stream>>>(s, wcmb, xt2, xrt2, hin, hout, cst,
                                        yf, ybr, bf, bb, lenp);
    }

    k_logits<<<1024, 256, 0, stream>>>(yf, ybr, wc, bc, L1p, L2p);
    k_combine<<<128, 256, 0, stream>>>(L1p, L2p, lenp, out + OFF_LOGITS);
    k_crf_nll<<<64, 64, 0, stream>>>(out + OFF_LOGITS, labels, lenp, cs, ce, ctr, llhp);
    k_loss<<<1, 64, 0, stream>>>(llhp, lenp, out);
    k_viterbi<<<64, 64, 0, stream>>>(out + OFF_LOGITS, lenp, cs, ce, ctr,
                                     out + OFF_TAGS, out + OFF_MASK);
}

// Round 4
// 16377.899 us; speedup vs baseline: 3.5776x; 1.3428x over previous
//
#include <hip/hip_runtime.h>
#include <math.h>

#define B_ 64
#define S_ 512
#define I_ 300
#define H_ 512
#define G_ 2048   // 4*H
#define T_ 25
#define K_ 812    // I_ + H_
#define KQ_ 203   // K_/4 float4 groups per weight row
#define IQ_ 75    // I_/4
#define HQ_ 128   // H_/4

// ---------------- workspace layout (float elements) ----------------
static constexpr size_t SZ_XT   = (size_t)S_ * I_ * B_;        // 9,830,400
static constexpr size_t OFS_XT  = 0;                            // xt4 [s][i4][b][4]
static constexpr size_t OFS_XRT = OFS_XT + SZ_XT;               // xrt4 reversed
static constexpr size_t SZ_WC   = (size_t)2 * G_ * K_;          // 3,325,952
static constexpr size_t OFS_WC  = OFS_XRT + SZ_XT;              // w4 [dir][u][g][k4][4]
static constexpr size_t OFS_H0  = OFS_WC + SZ_WC;               // h4 [dir][k4][b][4]
static constexpr size_t OFS_H1  = OFS_H0 + (size_t)2 * H_ * B_;
static constexpr size_t OFS_C   = OFS_H1 + (size_t)2 * H_ * B_; // cst [dir][u][b]
static constexpr size_t OFS_YF  = OFS_C + (size_t)2 * H_ * B_;  // [s][h][b]
static constexpr size_t SZ_Y    = (size_t)S_ * H_ * B_;         // 16,777,216
static constexpr size_t OFS_YB  = OFS_YF + SZ_Y;
static constexpr size_t SZ_L    = (size_t)B_ * S_ * T_;         // 819,200
static constexpr size_t OFS_L1  = OFS_YB + SZ_Y;
static constexpr size_t OFS_L2  = OFS_L1 + SZ_L;
static constexpr size_t OFS_LEN = OFS_L2 + SZ_L;   // int32[64]
static constexpr size_t OFS_LLH = OFS_LEN + 64;    // float[64]

// output layout (float elements in d_out)
static constexpr size_t OFF_LOGITS = 1;
static constexpr size_t OFF_TAGS   = 1 + SZ_L;
static constexpr size_t OFF_MASK   = OFF_TAGS + (size_t)B_ * S_;

// ---------------- small utility kernels ----------------
__global__ void k_lengths(const int* __restrict__ am, int* __restrict__ len) {
    int b = threadIdx.x;
    int sum = 0;
    for (int s = 0; s < S_; ++s) sum += am[b * S_ + s];
    len[b] = sum;
}

__global__ void k_zero(float* __restrict__ p, int n) {
    int idx = blockIdx.x * 256 + threadIdx.x;
    if (idx < n) p[idx] = 0.f;
}

// w4[dir][u(512)][g(4)][k4(203)][4] = [W_ih row | W_hh row] quad-packed.
__global__ void k_prep_w4(const float* __restrict__ wihf, const float* __restrict__ whhf,
                          const float* __restrict__ wihb, const float* __restrict__ whhb,
                          float* __restrict__ w4) {
    size_t total = (size_t)2 * H_ * 4 * KQ_ * 4;
    for (size_t idx = (size_t)blockIdx.x * 256 + threadIdx.x; idx < total;
         idx += (size_t)gridDim.x * 256) {
        int j = (int)(idx & 3);
        size_t t = idx >> 2;
        int k4 = (int)(t % KQ_); t /= KQ_;
        int g = (int)(t & 3); t >>= 2;
        int u = (int)(t % H_);
        int dir = (int)(t / H_);
        int k = k4 * 4 + j;
        int row = g * H_ + u;
        const float* wih = dir ? wihb : wihf;
        const float* whh = dir ? whhb : whhf;
        w4[idx] = (k < I_) ? wih[(size_t)row * I_ + k]
                           : whh[(size_t)row * H_ + (k - I_)];
    }
}

// x[b][s][i] -> xt4[s][i4][b][4]; rev variant gathers per-batch reversed rows.
__global__ __launch_bounds__(256) void k_xpose4(const float* __restrict__ x,
                                                const int* __restrict__ len,
                                                float* __restrict__ xt4,
                                                float* __restrict__ xrt4) {
    __shared__ int lsrc[B_];
    int s = blockIdx.x & 511, isrev = blockIdx.x >> 9;  // grid = 1024
    int tid = threadIdx.x;
    if (tid < B_) {
        int src = s;
        if (isrev) { int L = len[tid]; src = (s < L) ? (L - 1 - s) : s; }
        lsrc[tid] = src;
    }
    __syncthreads();
    float* dst = (isrev ? xrt4 : xt4) + (size_t)s * I_ * B_;
    for (int dw = tid; dw < I_ * B_; dw += 256) {
        int i4 = dw >> 8;          // / 256
        int r = dw & 255;
        int b = r >> 2, j = r & 3;
        int i = i4 * 4 + j;
        dst[dw] = x[((size_t)b * S_ + lsrc[b]) * I_ + i];
    }
}

// ---------------- one BiLSTM time step (split-K over waves) ----------------
// 256 blocks x 256 threads. dir = bid>>7; block owns 4 units u = (bid&127)*4+uu.
// Wave wq computes PARTIAL sums for all 16 (unit,gate) rows over its K-quarter:
// acts (x from xt4 [s][i4][b][4], h from h4 [dir][k4][b][4]) as coalesced
// per-lane float4 loads (lane=batch, 1 KB/instr); weights as wave-uniform
// broadcast float4 loads. Partials combined via 16 KB LDS; wave wq finalizes
// unit uu=wq (bias + nonlinearity + state update).
__global__ __launch_bounds__(256) void k_step4(
    int s,
    const float* __restrict__ w4,
    const float* __restrict__ xt4, const float* __restrict__ xrt4,
    const float* __restrict__ hin4, float* __restrict__ hout4,
    float* __restrict__ cst,
    float* __restrict__ yf, float* __restrict__ ybr,
    const float* __restrict__ bf, const float* __restrict__ bb,
    const int* __restrict__ len) {
    __shared__ float parts[4 * 16 * B_];   // [w][uu*4+g][lane], 16 KB
    const int dir = blockIdx.x >> 7;
    const int ug  = blockIdx.x & 127;
    const int tid = threadIdx.x;
    const int lane = tid & 63;
    const int wq = __builtin_amdgcn_readfirstlane(tid >> 6);

    const float4* xa4 = (const float4*)(dir ? xrt4 : xt4) + (size_t)s * IQ_ * B_ + lane;
    const float4* ha4 = (const float4*)hin4 + (size_t)dir * HQ_ * B_ + lane;
    const float4* wv  = (const float4*)w4;
    const size_t wbase = (((size_t)dir * H_ + (ug << 2)) * 4) * KQ_;

    float acc[16];
#pragma unroll
    for (int i = 0; i < 16; ++i) acc[i] = 0.f;

    const int lo = wq * 51;
    const int hi = (wq == 3) ? KQ_ : lo + 51;
    const int xhi = hi < IQ_ ? hi : IQ_;
    for (int k4 = lo; k4 < xhi; ++k4) {
        float4 a = xa4[(size_t)k4 * B_];
#pragma unroll
        for (int r = 0; r < 16; ++r) {
            float4 w = wv[wbase + (size_t)r * KQ_ + k4];
            acc[r] += a.x * w.x + a.y * w.y + a.z * w.z + a.w * w.w;
        }
    }
    const int hlo = (lo > IQ_ ? lo : IQ_) - IQ_;
    const int hhi = hi - IQ_;
    for (int k4 = hlo; k4 < hhi; ++k4) {
        float4 a = ha4[(size_t)k4 * B_];
#pragma unroll
        for (int r = 0; r < 16; ++r) {
            float4 w = wv[wbase + (size_t)r * KQ_ + (k4 + IQ_)];
            acc[r] += a.x * w.x + a.y * w.y + a.z * w.z + a.w * w.w;
        }
    }

#pragma unroll
    for (int r = 0; r < 16; ++r) parts[(wq * 16 + r) * B_ + lane] = acc[r];
    __syncthreads();

    // wave wq finalizes unit uu = wq
    const int u = (ug << 2) + wq;
    const float* bias = dir ? bb : bf;
    float g4[4];
#pragma unroll
    for (int g = 0; g < 4; ++g) {
        float v = bias[g * H_ + u];
#pragma unroll
        for (int w = 0; w < 4; ++w) v += parts[(w * 16 + wq * 4 + g) * B_ + lane];
        g4[g] = v;
    }
    const int L = len[lane];
    const bool valid = (s < L);
    const size_t cidx = ((size_t)dir * H_ + u) * B_ + lane;
    const size_t hidx = ((((size_t)dir * HQ_ + ug) * B_ + lane) << 2) + wq;
    float hp = hin4[hidx];
    float cp = cst[cidx];
    float ii = 1.f / (1.f + expf(-g4[0]));
    float ff = 1.f / (1.f + expf(-g4[1]));
    float gg = tanhf(g4[2]);
    float oo = 1.f / (1.f + expf(-g4[3]));
    float cn = ff * cp + ii * gg;
    float hn = oo * tanhf(cn);
    hout4[hidx] = valid ? hn : hp;
    if (valid) cst[cidx] = cn;
    (dir ? ybr : yf)[(((size_t)s * H_ + u) << 6) + lane] = valid ? hn : 0.f;
}

// ---------------- logits / CRF epilogue ----------------
__global__ __launch_bounds__(256) void k_logits(const float* __restrict__ yf,
                                                const float* __restrict__ ybr,
                                                const float* __restrict__ wc,
                                                const float* __restrict__ bcv,
                                                float* __restrict__ L1,
                                                float* __restrict__ L2p) {
    __shared__ float smem[T_ * H_];
    int part = blockIdx.x >> 9;
    int s = blockIdx.x & 511;
    int tid = threadIdx.x;
    const float* y = part ? ybr : yf;
    float* Ldst = part ? L2p : L1;
    for (int idx = tid; idx < T_ * H_; idx += 256) {
        int t = idx >> 9;
        int h = idx & 511;
        smem[idx] = wc[(size_t)t * 1024 + part * 512 + h];
    }
    __syncthreads();
    int q = tid >> 6, b = tid & 63;
    float acc[T_];
#pragma unroll
    for (int t = 0; t < T_; ++t) acc[t] = 0.f;
    const float* yrow = y + (size_t)s * H_ * B_ + b;
    for (int h = q * 128; h < q * 128 + 128; ++h) {
        float a = yrow[(size_t)h * B_];
#pragma unroll
        for (int t = 0; t < T_; ++t) acc[t] += a * smem[t * H_ + h];
    }
    __syncthreads();
    float* pl = smem;
#pragma unroll
    for (int t = 0; t < T_; ++t) pl[(q * 64 + b) * 26 + t] = acc[t];
    __syncthreads();
    for (int idx = tid; idx < B_ * T_; idx += 256) {
        int bb2 = idx / T_;
        int t = idx - bb2 * T_;
        float v = pl[(0 * 64 + bb2) * 26 + t] + pl[(1 * 64 + bb2) * 26 + t] +
                  pl[(2 * 64 + bb2) * 26 + t] + pl[(3 * 64 + bb2) * 26 + t];
        if (!part) v += bcv[t];
        Ldst[((size_t)bb2 * S_ + s) * T_ + t] = v;
    }
}

__global__ void k_combine(const float* __restrict__ L1, const float* __restrict__ L2p,
                          const int* __restrict__ len, float* __restrict__ outlog) {
    int id = blockIdx.x * 256 + threadIdx.x;  // 32768 = B*S
    int b = id >> 9;
    int s = id & 511;
    int L = len[b];
    int sr = (s < L) ? (L - 1 - s) : s;
    const float* p1 = L1 + ((size_t)b * S_ + s) * T_;
    const float* p2 = L2p + ((size_t)b * S_ + sr) * T_;
    float* o = outlog + ((size_t)b * S_ + s) * T_;
#pragma unroll
    for (int t = 0; t < T_; ++t) o[t] = p1[t] + p2[t];
}

__global__ __launch_bounds__(64) void k_crf_nll(const float* __restrict__ em,
                                                const int* __restrict__ labels,
                                                const int* __restrict__ len,
                                                const float* __restrict__ cs,
                                                const float* __restrict__ ce,
                                                const float* __restrict__ ctr,
                                                float* __restrict__ llh) {
    int b = blockIdx.x, tid = threadIdx.x;
    __shared__ float tr[T_ * T_];
    __shared__ float sa[T_], sb[T_];
    for (int idx = tid; idx < T_ * T_; idx += 64) tr[idx] = ctr[idx];
    const float* e = em + (size_t)b * S_ * T_;
    int L = len[b];
    if (tid < T_) sa[tid] = cs[tid] + e[tid];
    __syncthreads();
    float* cur = sa;
    float* nx = sb;
    for (int t = 1; t < L; ++t) {
        if (tid < T_) {
            float m = -1e30f;
            for (int i = 0; i < T_; ++i) m = fmaxf(m, cur[i] + tr[i * T_ + tid]);
            float ssum = 0.f;
            for (int i = 0; i < T_; ++i) ssum += expf(cur[i] + tr[i * T_ + tid] - m);
            nx[tid] = m + logf(ssum) + e[(size_t)t * T_ + tid];
        }
        __syncthreads();
        float* tmp = cur; cur = nx; nx = tmp;
    }
    float part = 0.f;
    for (int t = tid; t < S_; t += 64) {
        if (t >= 1 && t < L) {
            int lp = labels[b * S_ + t - 1];
            int lc = labels[b * S_ + t];
            part += tr[lp * T_ + lc] + e[(size_t)t * T_ + lc];
        }
    }
    for (int off = 32; off; off >>= 1) part += __shfl_down(part, off, 64);
    if (tid == 0) {
        float m = -1e30f;
        for (int j = 0; j < T_; ++j) m = fmaxf(m, cur[j] + ce[j]);
        float ssum = 0.f;
        for (int j = 0; j < T_; ++j) ssum += expf(cur[j] + ce[j] - m);
        float denom = m + logf(ssum);
        int l0 = labels[b * S_];
        int lL = labels[b * S_ + L - 1];
        float num = cs[l0] + e[l0] + part + ce[lL];
        llh[b] = num - denom;
    }
}

__global__ void k_loss(const float* __restrict__ llh, const int* __restrict__ len,
                       float* __restrict__ out0) {
    int tid = threadIdx.x;
    float v = llh[tid];
    float n = (float)len[tid];
    for (int off = 32; off; off >>= 1) {
        v += __shfl_down(v, off, 64);
        n += __shfl_down(n, off, 64);
    }
    if (tid == 0) out0[0] = -(v / n);
}

__global__ __launch_bounds__(64) void k_viterbi(const float* __restrict__ em,
                                                const int* __restrict__ len,
                                                const float* __restrict__ cs,
                                                const float* __restrict__ ce,
                                                const float* __restrict__ ctr,
                                                float* __restrict__ otags,
                                                float* __restrict__ omask) {
    int b = blockIdx.x, tid = threadIdx.x;
    __shared__ float tr[T_ * T_];
    __shared__ float sa[T_], sb[T_];
    __shared__ unsigned char hist[(S_ - 1) * T_];
    __shared__ unsigned char tg[S_];
    for (int idx = tid; idx < T_ * T_; idx += 64) tr[idx] = ctr[idx];
    const float* e = em + (size_t)b * S_ * T_;
    int L = len[b];
    if (tid < T_) sa[tid] = cs[tid] + e[tid];
    __syncthreads();
    float* cur = sa;
    float* nx = sb;
    for (int t = 1; t < L; ++t) {
        if (tid < T_) {
            float best = -1e30f;
            int bi = 0;
            for (int i = 0; i < T_; ++i) {
                float v = cur[i] + tr[i * T_ + tid];
                if (v > best) { best = v; bi = i; }
            }
            nx[tid] = best + e[(size_t)t * T_ + tid];
            hist[(t - 1) * T_ + tid] = (unsigned char)bi;
        }
        __syncthreads();
        float* tmp = cur; cur = nx; nx = tmp;
    }
    if (tid == 0) {
        float best = -1e30f;
        int bt = 0;
        for (int j = 0; j < T_; ++j) {
            float v = cur[j] + ce[j];
            if (v > best) { best = v; bt = j; }
        }
        tg[S_ - 1] = (unsigned char)bt;
        for (int t = S_ - 2; t >= 0; --t) {
            if (t + 1 < L) bt = hist[t * T_ + bt];
            tg[t] = (unsigned char)bt;
        }
    }
    __syncthreads();
    for (int idx = tid; idx < S_; idx += 64) {
        otags[(size_t)b * S_ + idx] = (float)tg[idx];
        omask[(size_t)b * S_ + idx] = (idx < L) ? 1.f : 0.f;
    }
}

// ---------------- host launch ----------------
extern "C" void kernel_launch(void* const* d_in, const int* in_sizes, int n_in,
                              void* d_out, int out_size, void* d_ws, size_t ws_size,
                              hipStream_t stream) {
    const float* x    = (const float*)d_in[0];
    const float* wihf = (const float*)d_in[1];
    const float* whhf = (const float*)d_in[2];
    const float* bf   = (const float*)d_in[3];
    const float* wihb = (const float*)d_in[4];
    const float* whhb = (const float*)d_in[5];
    const float* bb   = (const float*)d_in[6];
    const float* wc   = (const float*)d_in[7];
    const float* bc   = (const float*)d_in[8];
    const float* cs   = (const float*)d_in[9];
    const float* ce   = (const float*)d_in[10];
    const float* ctr  = (const float*)d_in[11];
    const int* am     = (const int*)d_in[12];
    const int* labels = (const int*)d_in[13];

    float* ws   = (float*)d_ws;
    float* xt4  = ws + OFS_XT;
    float* xrt4 = ws + OFS_XRT;
    float* w4   = ws + OFS_WC;
    float* h4a  = ws + OFS_H0;
    float* h4b  = ws + OFS_H1;
    float* cst  = ws + OFS_C;
    float* yf   = ws + OFS_YF;
    float* ybr  = ws + OFS_YB;
    float* L1p  = ws + OFS_L1;
    float* L2p  = ws + OFS_L2;
    int*   lenp = (int*)(ws + OFS_LEN);
    float* llhp = ws + OFS_LLH;
    float* out  = (float*)d_out;

    k_lengths<<<1, 64, 0, stream>>>(am, lenp);
    k_prep_w4<<<2048, 256, 0, stream>>>(wihf, whhf, wihb, whhb, w4);
    k_zero<<<768, 256, 0, stream>>>(h4a, 3 * 2 * H_ * B_);  // h4a, h4b, cst
    k_xpose4<<<1024, 256, 0, stream>>>(x, lenp, xt4, xrt4);

    for (int s = 0; s < S_; ++s) {
        const float* hin = (s & 1) ? h4b : h4a;
        float* hout      = (s & 1) ? h4a : h4b;
        k_step4<<<256, 256, 0, stream>>>(s, w4, xt4, xrt4, hin, hout, cst,
                                         yf, ybr, bf, bb, lenp);
    }

    k_logits<<<1024, 256, 0, stream>>>(yf, ybr, wc, bc, L1p, L2p);
    k_combine<<<128, 256, 0, stream>>>(L1p, L2p, lenp, out + OFF_LOGITS);
    k_crf_nll<<<64, 64, 0, stream>>>(out + OFF_LOGITS, labels, lenp, cs, ce, ctr, llhp);
    k_loss<<<1, 64, 0, stream>>>(llhp, lenp, out);
    k_viterbi<<<64, 64, 0, stream>>>(out + OFF_LOGITS, lenp, cs, ce, ctr,
                                     out + OFF_TAGS, out + OFF_MASK);
}

// Round 5
// 11933.266 us; speedup vs baseline: 4.9102x; 1.3725x over previous
//
#include <hip/hip_runtime.h>
#include <math.h>

#define B_ 64
#define S_ 512
#define I_ 300
#define H_ 512
#define G_ 2048   // 4*H
#define T_ 25
#define K_ 812    // I_ + H_
#define KQ_ 203   // K_/4 float4 groups per weight row
#define IQ_ 75    // I_/4
#define HQ_ 128   // H_/4

// ---------------- workspace layout (float elements) ----------------
static constexpr size_t SZ_XT   = (size_t)S_ * I_ * B_;        // 9,830,400
static constexpr size_t OFS_XT  = 0;                            // xt4 [s][i4][b][4]
static constexpr size_t OFS_XRT = OFS_XT + SZ_XT;               // xrt4 reversed
static constexpr size_t SZ_WC   = (size_t)2 * G_ * K_;          // 3,325,952
static constexpr size_t OFS_WC  = OFS_XRT + SZ_XT;              // w4 [dir][u][g][k4][4]
static constexpr size_t OFS_H0  = OFS_WC + SZ_WC;               // h4 [dir][k4][b][4]
static constexpr size_t OFS_H1  = OFS_H0 + (size_t)2 * H_ * B_;
static constexpr size_t OFS_C   = OFS_H1 + (size_t)2 * H_ * B_; // cst [dir][u][b]
static constexpr size_t OFS_YF  = OFS_C + (size_t)2 * H_ * B_;  // [s][h][b]
static constexpr size_t SZ_Y    = (size_t)S_ * H_ * B_;         // 16,777,216
static constexpr size_t OFS_YB  = OFS_YF + SZ_Y;
static constexpr size_t SZ_L    = (size_t)B_ * S_ * T_;         // 819,200
static constexpr size_t OFS_L1  = OFS_YB + SZ_Y;
static constexpr size_t OFS_L2  = OFS_L1 + SZ_L;
static constexpr size_t OFS_LEN = OFS_L2 + SZ_L;   // int32[64]
static constexpr size_t OFS_LLH = OFS_LEN + 64;    // float[64]

// output layout (float elements in d_out)
static constexpr size_t OFF_LOGITS = 1;
static constexpr size_t OFF_TAGS   = 1 + SZ_L;
static constexpr size_t OFF_MASK   = OFF_TAGS + (size_t)B_ * S_;

// ---------------- small utility kernels ----------------
__global__ void k_lengths(const int* __restrict__ am, int* __restrict__ len) {
    int b = threadIdx.x;
    int sum = 0;
    for (int s = 0; s < S_; ++s) sum += am[b * S_ + s];
    len[b] = sum;
}

__global__ void k_zero(float* __restrict__ p, int n) {
    int idx = blockIdx.x * 256 + threadIdx.x;
    if (idx < n) p[idx] = 0.f;
}

// w4[dir][u(512)][g(4)][k4(203)][4] = [W_ih row | W_hh row] quad-packed.
__global__ void k_prep_w4(const float* __restrict__ wihf, const float* __restrict__ whhf,
                          const float* __restrict__ wihb, const float* __restrict__ whhb,
                          float* __restrict__ w4) {
    size_t total = (size_t)2 * H_ * 4 * KQ_ * 4;
    for (size_t idx = (size_t)blockIdx.x * 256 + threadIdx.x; idx < total;
         idx += (size_t)gridDim.x * 256) {
        int j = (int)(idx & 3);
        size_t t = idx >> 2;
        int k4 = (int)(t % KQ_); t /= KQ_;
        int g = (int)(t & 3); t >>= 2;
        int u = (int)(t % H_);
        int dir = (int)(t / H_);
        int k = k4 * 4 + j;
        int row = g * H_ + u;
        const float* wih = dir ? wihb : wihf;
        const float* whh = dir ? whhb : whhf;
        w4[idx] = (k < I_) ? wih[(size_t)row * I_ + k]
                           : whh[(size_t)row * H_ + (k - I_)];
    }
}

// x[b][s][i] -> xt4[s][i4][b][4]; rev variant gathers per-batch reversed rows.
__global__ __launch_bounds__(256) void k_xpose4(const float* __restrict__ x,
                                                const int* __restrict__ len,
                                                float* __restrict__ xt4,
                                                float* __restrict__ xrt4) {
    __shared__ int lsrc[B_];
    int s = blockIdx.x & 511, isrev = blockIdx.x >> 9;  // grid = 1024
    int tid = threadIdx.x;
    if (tid < B_) {
        int src = s;
        if (isrev) { int L = len[tid]; src = (s < L) ? (L - 1 - s) : s; }
        lsrc[tid] = src;
    }
    __syncthreads();
    float* dst = (isrev ? xrt4 : xt4) + (size_t)s * I_ * B_;
    for (int dw = tid; dw < I_ * B_; dw += 256) {
        int i4 = dw >> 8;          // / 256
        int r = dw & 255;
        int b = r >> 2, j = r & 3;
        int i = i4 * 4 + j;
        dst[dw] = x[((size_t)b * S_ + lsrc[b]) * I_ + i];
    }
}

// ---------------- one BiLSTM time step (8-way split-K over waves) ----------------
// 256 blocks x 512 threads (8 waves = 2/SIMD for latency hiding).
// dir = bid>>7; block owns 4 units u = (bid&127)*4+uu. Wave wq computes PARTIAL
// sums for all 16 (unit,gate) rows over its 26-quad K-chunk: acts as coalesced
// per-lane float4 loads (lane=batch), weights as wave-uniform s_load float4.
// Partials combined via 32 KB LDS; waves 0..3 finalize unit uu=wq.
__global__ __launch_bounds__(512) void k_step8(
    int s,
    const float* __restrict__ w4,
    const float* __restrict__ xt4, const float* __restrict__ xrt4,
    const float* __restrict__ hin4, float* __restrict__ hout4,
    float* __restrict__ cst,
    float* __restrict__ yf, float* __restrict__ ybr,
    const float* __restrict__ bf, const float* __restrict__ bb,
    const int* __restrict__ len) {
    __shared__ float parts[8 * 16 * B_];   // [w][uu*4+g][lane], 32 KB
    const int dir = blockIdx.x >> 7;
    const int ug  = blockIdx.x & 127;
    const int tid = threadIdx.x;
    const int lane = tid & 63;
    const int wq = __builtin_amdgcn_readfirstlane(tid >> 6);  // 0..7

    const float4* xa4 = (const float4*)(dir ? xrt4 : xt4) + (size_t)s * IQ_ * B_ + lane;
    const float4* ha4 = (const float4*)hin4 + (size_t)dir * HQ_ * B_ + lane;
    const float4* wv  = (const float4*)w4;
    const size_t wbase = (((size_t)dir * H_ + (ug << 2)) * 4) * KQ_;

    float acc[16];
#pragma unroll
    for (int i = 0; i < 16; ++i) acc[i] = 0.f;

    const int lo = wq * 26;                     // 8 chunks of 26 (last = 21)
    const int hi = (lo + 26 < KQ_) ? lo + 26 : KQ_;
    const int xhi = hi < IQ_ ? hi : IQ_;
    for (int k4 = lo; k4 < xhi; ++k4) {
        float4 a = xa4[(size_t)k4 * B_];
#pragma unroll
        for (int r = 0; r < 16; ++r) {
            float4 w = wv[wbase + (size_t)r * KQ_ + k4];
            acc[r] += a.x * w.x + a.y * w.y + a.z * w.z + a.w * w.w;
        }
    }
    const int hlo = (lo > IQ_ ? lo : IQ_) - IQ_;
    const int hhi = hi - IQ_;
    for (int k4 = hlo; k4 < hhi; ++k4) {
        float4 a = ha4[(size_t)k4 * B_];
#pragma unroll
        for (int r = 0; r < 16; ++r) {
            float4 w = wv[wbase + (size_t)r * KQ_ + (k4 + IQ_)];
            acc[r] += a.x * w.x + a.y * w.y + a.z * w.z + a.w * w.w;
        }
    }

#pragma unroll
    for (int r = 0; r < 16; ++r) parts[(wq * 16 + r) * B_ + lane] = acc[r];
    __syncthreads();

    // waves 0..3 finalize unit uu = wq
    if (tid < 256) {
        const int wq2 = tid >> 6;
        const int u = (ug << 2) + wq2;
        const float* bias = dir ? bb : bf;
        float g4[4];
#pragma unroll
        for (int g = 0; g < 4; ++g) {
            float v = bias[g * H_ + u];
#pragma unroll
            for (int w = 0; w < 8; ++w)
                v += parts[(w * 16 + wq2 * 4 + g) * B_ + lane];
            g4[g] = v;
        }
        const int L = len[lane];
        const bool valid = (s < L);
        const size_t cidx = ((size_t)dir * H_ + u) * B_ + lane;
        const size_t hidx = ((((size_t)dir * HQ_ + ug) * B_ + lane) << 2) + wq2;
        float hp = hin4[hidx];
        float cp = cst[cidx];
        float ii = 1.f / (1.f + expf(-g4[0]));
        float ff = 1.f / (1.f + expf(-g4[1]));
        float gg = tanhf(g4[2]);
        float oo = 1.f / (1.f + expf(-g4[3]));
        float cn = ff * cp + ii * gg;
        float hn = oo * tanhf(cn);
        hout4[hidx] = valid ? hn : hp;
        if (valid) cst[cidx] = cn;
        (dir ? ybr : yf)[(((size_t)s * H_ + u) << 6) + lane] = valid ? hn : 0.f;
    }
}

// ---------------- logits / CRF epilogue ----------------
__global__ __launch_bounds__(256) void k_logits(const float* __restrict__ yf,
                                                const float* __restrict__ ybr,
                                                const float* __restrict__ wc,
                                                const float* __restrict__ bcv,
                                                float* __restrict__ L1,
                                                float* __restrict__ L2p) {
    __shared__ float smem[T_ * H_];
    int part = blockIdx.x >> 9;
    int s = blockIdx.x & 511;
    int tid = threadIdx.x;
    const float* y = part ? ybr : yf;
    float* Ldst = part ? L2p : L1;
    for (int idx = tid; idx < T_ * H_; idx += 256) {
        int t = idx >> 9;
        int h = idx & 511;
        smem[idx] = wc[(size_t)t * 1024 + part * 512 + h];
    }
    __syncthreads();
    int q = tid >> 6, b = tid & 63;
    float acc[T_];
#pragma unroll
    for (int t = 0; t < T_; ++t) acc[t] = 0.f;
    const float* yrow = y + (size_t)s * H_ * B_ + b;
    for (int h = q * 128; h < q * 128 + 128; ++h) {
        float a = yrow[(size_t)h * B_];
#pragma unroll
        for (int t = 0; t < T_; ++t) acc[t] += a * smem[t * H_ + h];
    }
    __syncthreads();
    float* pl = smem;
#pragma unroll
    for (int t = 0; t < T_; ++t) pl[(q * 64 + b) * 26 + t] = acc[t];
    __syncthreads();
    for (int idx = tid; idx < B_ * T_; idx += 256) {
        int bb2 = idx / T_;
        int t = idx - bb2 * T_;
        float v = pl[(0 * 64 + bb2) * 26 + t] + pl[(1 * 64 + bb2) * 26 + t] +
                  pl[(2 * 64 + bb2) * 26 + t] + pl[(3 * 64 + bb2) * 26 + t];
        if (!part) v += bcv[t];
        Ldst[((size_t)bb2 * S_ + s) * T_ + t] = v;
    }
}

__global__ void k_combine(const float* __restrict__ L1, const float* __restrict__ L2p,
                          const int* __restrict__ len, float* __restrict__ outlog) {
    int id = blockIdx.x * 256 + threadIdx.x;  // 32768 = B*S
    int b = id >> 9;
    int s = id & 511;
    int L = len[b];
    int sr = (s < L) ? (L - 1 - s) : s;
    const float* p1 = L1 + ((size_t)b * S_ + s) * T_;
    const float* p2 = L2p + ((size_t)b * S_ + sr) * T_;
    float* o = outlog + ((size_t)b * S_ + s) * T_;
#pragma unroll
    for (int t = 0; t < T_; ++t) o[t] = p1[t] + p2[t];
}

__global__ __launch_bounds__(64) void k_crf_nll(const float* __restrict__ em,
                                                const int* __restrict__ labels,
                                                const int* __restrict__ len,
                                                const float* __restrict__ cs,
                                                const float* __restrict__ ce,
                                                const float* __restrict__ ctr,
                                                float* __restrict__ llh) {
    int b = blockIdx.x, tid = threadIdx.x;
    __shared__ float tr[T_ * T_];
    __shared__ float sa[T_], sb[T_];
    for (int idx = tid; idx < T_ * T_; idx += 64) tr[idx] = ctr[idx];
    const float* e = em + (size_t)b * S_ * T_;
    int L = len[b];
    if (tid < T_) sa[tid] = cs[tid] + e[tid];
    __syncthreads();
    float* cur = sa;
    float* nx = sb;
    for (int t = 1; t < L; ++t) {
        if (tid < T_) {
            float m = -1e30f;
            for (int i = 0; i < T_; ++i) m = fmaxf(m, cur[i] + tr[i * T_ + tid]);
            float ssum = 0.f;
            for (int i = 0; i < T_; ++i) ssum += expf(cur[i] + tr[i * T_ + tid] - m);
            nx[tid] = m + logf(ssum) + e[(size_t)t * T_ + tid];
        }
        __syncthreads();
        float* tmp = cur; cur = nx; nx = tmp;
    }
    float part = 0.f;
    for (int t = tid; t < S_; t += 64) {
        if (t >= 1 && t < L) {
            int lp = labels[b * S_ + t - 1];
            int lc = labels[b * S_ + t];
            part += tr[lp * T_ + lc] + e[(size_t)t * T_ + lc];
        }
    }
    for (int off = 32; off; off >>= 1) part += __shfl_down(part, off, 64);
    if (tid == 0) {
        float m = -1e30f;
        for (int j = 0; j < T_; ++j) m = fmaxf(m, cur[j] + ce[j]);
        float ssum = 0.f;
        for (int j = 0; j < T_; ++j) ssum += expf(cur[j] + ce[j] - m);
        float denom = m + logf(ssum);
        int l0 = labels[b * S_];
        int lL = labels[b * S_ + L - 1];
        float num = cs[l0] + e[l0] + part + ce[lL];
        llh[b] = num - denom;
    }
}

__global__ void k_loss(const float* __restrict__ llh, const int* __restrict__ len,
                       float* __restrict__ out0) {
    int tid = threadIdx.x;
    float v = llh[tid];
    float n = (float)len[tid];
    for (int off = 32; off; off >>= 1) {
        v += __shfl_down(v, off, 64);
        n += __shfl_down(n, off, 64);
    }
    if (tid == 0) out0[0] = -(v / n);
}

__global__ __launch_bounds__(64) void k_viterbi(const float* __restrict__ em,
                                                const int* __restrict__ len,
                                                const float* __restrict__ cs,
                                                const float* __restrict__ ce,
                                                const float* __restrict__ ctr,
                                                float* __restrict__ otags,
                                                float* __restrict__ omask) {
    int b = blockIdx.x, tid = threadIdx.x;
    __shared__ float tr[T_ * T_];
    __shared__ float sa[T_], sb[T_];
    __shared__ unsigned char hist[(S_ - 1) * T_];
    __shared__ unsigned char tg[S_];
    for (int idx = tid; idx < T_ * T_; idx += 64) tr[idx] = ctr[idx];
    const float* e = em + (size_t)b * S_ * T_;
    int L = len[b];
    if (tid < T_) sa[tid] = cs[tid] + e[tid];
    __syncthreads();
    float* cur = sa;
    float* nx = sb;
    for (int t = 1; t < L; ++t) {
        if (tid < T_) {
            float best = -1e30f;
            int bi = 0;
            for (int i = 0; i < T_; ++i) {
                float v = cur[i] + tr[i * T_ + tid];
                if (v > best) { best = v; bi = i; }
            }
            nx[tid] = best + e[(size_t)t * T_ + tid];
            hist[(t - 1) * T_ + tid] = (unsigned char)bi;
        }
        __syncthreads();
        float* tmp = cur; cur = nx; nx = tmp;
    }
    if (tid == 0) {
        float best = -1e30f;
        int bt = 0;
        for (int j = 0; j < T_; ++j) {
            float v = cur[j] + ce[j];
            if (v > best) { best = v; bt = j; }
        }
        tg[S_ - 1] = (unsigned char)bt;
        for (int t = S_ - 2; t >= 0; --t) {
            if (t + 1 < L) bt = hist[t * T_ + bt];
            tg[t] = (unsigned char)bt;
        }
    }
    __syncthreads();
    for (int idx = tid; idx < S_; idx += 64) {
        otags[(size_t)b * S_ + idx] = (float)tg[idx];
        omask[(size_t)b * S_ + idx] = (idx < L) ? 1.f : 0.f;
    }
}

// ---------------- host launch ----------------
extern "C" void kernel_launch(void* const* d_in, const int* in_sizes, int n_in,
                              void* d_out, int out_size, void* d_ws, size_t ws_size,
                              hipStream_t stream) {
    const float* x    = (const float*)d_in[0];
    const float* wihf = (const float*)d_in[1];
    const float* whhf = (const float*)d_in[2];
    const float* bf   = (const float*)d_in[3];
    const float* wihb = (const float*)d_in[4];
    const float* whhb = (const float*)d_in[5];
    const float* bb   = (const float*)d_in[6];
    const float* wc   = (const float*)d_in[7];
    const float* bc   = (const float*)d_in[8];
    const float* cs   = (const float*)d_in[9];
    const float* ce   = (const float*)d_in[10];
    const float* ctr  = (const float*)d_in[11];
    const int* am     = (const int*)d_in[12];
    const int* labels = (const int*)d_in[13];

    float* ws   = (float*)d_ws;
    float* xt4  = ws + OFS_XT;
    float* xrt4 = ws + OFS_XRT;
    float* w4   = ws + OFS_WC;
    float* h4a  = ws + OFS_H0;
    float* h4b  = ws + OFS_H1;
    float* cst  = ws + OFS_C;
    float* yf   = ws + OFS_YF;
    float* ybr  = ws + OFS_YB;
    float* L1p  = ws + OFS_L1;
    float* L2p  = ws + OFS_L2;
    int*   lenp = (int*)(ws + OFS_LEN);
    float* llhp = ws + OFS_LLH;
    float* out  = (float*)d_out;

    k_lengths<<<1, 64, 0, stream>>>(am, lenp);
    k_prep_w4<<<2048, 256, 0, stream>>>(wihf, whhf, wihb, whhb, w4);
    k_zero<<<768, 256, 0, stream>>>(h4a, 3 * 2 * H_ * B_);  // h4a, h4b, cst
    k_xpose4<<<1024, 256, 0, stream>>>(x, lenp, xt4, xrt4);

    for (int s = 0; s < S_; ++s) {
        const float* hin = (s & 1) ? h4b : h4a;
        float* hout      = (s & 1) ? h4a : h4b;
        k_step8<<<256, 512, 0, stream>>>(s, w4, xt4, xrt4, hin, hout, cst,
                                         yf, ybr, bf, bb, lenp);
    }

    k_logits<<<1024, 256, 0, stream>>>(yf, ybr, wc, bc, L1p, L2p);
    k_combine<<<128, 256, 0, stream>>>(L1p, L2p, lenp, out + OFF_LOGITS);
    k_crf_nll<<<64, 64, 0, stream>>>(out + OFF_LOGITS, labels, lenp, cs, ce, ctr, llhp);
    k_loss<<<1, 64, 0, stream>>>(llhp, lenp, out);
    k_viterbi<<<64, 64, 0, stream>>>(out + OFF_LOGITS, lenp, cs, ce, ctr,
                                     out + OFF_TAGS, out + OFF_MASK);
}

// Round 6
// 8836.147 us; speedup vs baseline: 6.6312x; 1.3505x over previous
//
#include <hip/hip_runtime.h>
#include <math.h>

#define B_ 64
#define S_ 512
#define I_ 300
#define H_ 512
#define G_ 2048   // 4*H
#define T_ 25
#define K_ 812    // I_ + H_
#define KQ_ 203   // K_/4 float4 groups per weight row
#define IQ_ 75    // I_/4
#define HQ_ 128   // H_/4

// ---------------- workspace layout (float elements) ----------------
static constexpr size_t SZ_XT   = (size_t)S_ * I_ * B_;        // 9,830,400
static constexpr size_t OFS_XT  = 0;                            // xt4 [s][i4][b][4]
static constexpr size_t OFS_XRT = OFS_XT + SZ_XT;               // xrt4 reversed
static constexpr size_t SZ_WC   = (size_t)2 * G_ * K_;          // 3,325,952
static constexpr size_t OFS_WC  = OFS_XRT + SZ_XT;              // w4 [dir][u][g][k4][4]
static constexpr size_t OFS_H0  = OFS_WC + SZ_WC;               // h4 [dir][k4][b][4]
static constexpr size_t OFS_H1  = OFS_H0 + (size_t)2 * H_ * B_;
static constexpr size_t OFS_C   = OFS_H1 + (size_t)2 * H_ * B_; // unused (c in regs)
static constexpr size_t OFS_YF  = OFS_C + (size_t)2 * H_ * B_;  // [s][h][b]
static constexpr size_t SZ_Y    = (size_t)S_ * H_ * B_;         // 16,777,216
static constexpr size_t OFS_YB  = OFS_YF + SZ_Y;
static constexpr size_t SZ_L    = (size_t)B_ * S_ * T_;         // 819,200
static constexpr size_t OFS_L1  = OFS_YB + SZ_Y;
static constexpr size_t OFS_L2  = OFS_L1 + SZ_L;
static constexpr size_t OFS_LEN = OFS_L2 + SZ_L;   // int32[64]
static constexpr size_t OFS_LLH = OFS_LEN + 64;    // float[64]
static constexpr size_t OFS_CNT = OFS_LLH + 64;    // int32[64] (2 used, 128B apart)

// output layout (float elements in d_out)
static constexpr size_t OFF_LOGITS = 1;
static constexpr size_t OFF_TAGS   = 1 + SZ_L;
static constexpr size_t OFF_MASK   = OFF_TAGS + (size_t)B_ * S_;

// ---------------- small utility kernels ----------------
__global__ void k_lengths(const int* __restrict__ am, int* __restrict__ len) {
    int b = threadIdx.x;
    int sum = 0;
    for (int s = 0; s < S_; ++s) sum += am[b * S_ + s];
    len[b] = sum;
}

__global__ void k_zero(float* __restrict__ p, int n) {
    int idx = blockIdx.x * 256 + threadIdx.x;
    if (idx < n) p[idx] = 0.f;
}

// w4[dir][u(512)][g(4)][k4(203)][4] = [W_ih row | W_hh row] quad-packed.
__global__ void k_prep_w4(const float* __restrict__ wihf, const float* __restrict__ whhf,
                          const float* __restrict__ wihb, const float* __restrict__ whhb,
                          float* __restrict__ w4) {
    size_t total = (size_t)2 * H_ * 4 * KQ_ * 4;
    for (size_t idx = (size_t)blockIdx.x * 256 + threadIdx.x; idx < total;
         idx += (size_t)gridDim.x * 256) {
        int j = (int)(idx & 3);
        size_t t = idx >> 2;
        int k4 = (int)(t % KQ_); t /= KQ_;
        int g = (int)(t & 3); t >>= 2;
        int u = (int)(t % H_);
        int dir = (int)(t / H_);
        int k = k4 * 4 + j;
        int row = g * H_ + u;
        const float* wih = dir ? wihb : wihf;
        const float* whh = dir ? whhb : whhf;
        w4[idx] = (k < I_) ? wih[(size_t)row * I_ + k]
                           : whh[(size_t)row * H_ + (k - I_)];
    }
}

// x[b][s][i] -> xt4[s][i4][b][4]; rev variant gathers per-batch reversed rows.
__global__ __launch_bounds__(256) void k_xpose4(const float* __restrict__ x,
                                                const int* __restrict__ len,
                                                float* __restrict__ xt4,
                                                float* __restrict__ xrt4) {
    __shared__ int lsrc[B_];
    int s = blockIdx.x & 511, isrev = blockIdx.x >> 9;  // grid = 1024
    int tid = threadIdx.x;
    if (tid < B_) {
        int src = s;
        if (isrev) { int L = len[tid]; src = (s < L) ? (L - 1 - s) : s; }
        lsrc[tid] = src;
    }
    __syncthreads();
    float* dst = (isrev ? xrt4 : xt4) + (size_t)s * I_ * B_;
    for (int dw = tid; dw < I_ * B_; dw += 256) {
        int i4 = dw >> 8;          // / 256
        int r = dw & 255;
        int b = r >> 2, j = r & 3;
        int i = i4 * 4 + j;
        dst[dw] = x[((size_t)b * S_ + lsrc[b]) * I_ + i];
    }
}

// ---------------- persistent BiLSTM scan, flag-based sync ----------------
// 256 blocks x 512 threads (cooperative launch for co-residency; NO grid.sync).
// Block = (dir, ug) owns units u = ug*4+0..3. Wave wq handles k4 = wq mod 8
// (strided: ~9 x-quads before the barrier wait, 16 h-quads after).
// Weights/x: normal cached loads -> L1/L2-resident across all 512 steps.
// h exchange: __hip_atomic_{load,store} RELAXED/AGENT (per-address coherent,
// bypasses non-coherent caches, NO cache-flush instructions ever execute).
// Arrival: per-dir IF counter after explicit vmcnt(0) drain + block barrier.
// c and own-h live in registers for the whole scan.
__global__ __launch_bounds__(512) void k_scan(
    const float* __restrict__ w4,
    const float* __restrict__ xt4, const float* __restrict__ xrt4,
    float* __restrict__ ha, float* __restrict__ hb,
    float* __restrict__ yf, float* __restrict__ ybr,
    const float* __restrict__ bf, const float* __restrict__ bb,
    const int* __restrict__ len, int* __restrict__ cnt) {
    __shared__ float parts[8 * 16 * B_];   // 32 KB
    const int dir = blockIdx.x >> 7;
    const int ug  = blockIdx.x & 127;
    const int tid = threadIdx.x;
    const int lane = tid & 63;
    const int wq = __builtin_amdgcn_readfirstlane(tid >> 6);  // 0..7

    const float4* __restrict__ wv = (const float4*)w4;
    const size_t wbase = (((size_t)dir * H_ + (ug << 2)) * 4) * KQ_;
    const float4* __restrict__ xall =
        (const float4*)(dir ? xrt4 : xt4);
    float* __restrict__ ybase = dir ? ybr : yf;
    int* const cn = cnt + dir * 32;     // 128 B apart

    // finalizer (waves 0..3) persistent state
    const int uF = (ug << 2) + wq;      // valid when wq<4
    float c_reg = 0.f, h_reg = 0.f;
    float bi0 = 0.f, bi1 = 0.f, bi2 = 0.f, bi3 = 0.f;
    if (wq < 4) {
        const float* bias = dir ? bb : bf;
        bi0 = bias[uF]; bi1 = bias[H_ + uF];
        bi2 = bias[2 * H_ + uF]; bi3 = bias[3 * H_ + uF];
    }
    const int Lb = len[lane];

    // first strided k4 >= IQ_ for this wave
    const int k4h0 = wq + (((IQ_ - wq + 7) >> 3) << 3);

    for (int s = 0; s < S_; ++s) {
        const float4* __restrict__ xa4 = xall + (size_t)s * IQ_ * B_ + lane;
        float acc[16];
#pragma unroll
        for (int i = 0; i < 16; ++i) acc[i] = 0.f;

        // ---- x-part (h-independent): runs before the wait ----
        for (int k4 = wq; k4 < IQ_; k4 += 8) {
            float4 a = xa4[(size_t)k4 * B_];
#pragma unroll
            for (int r = 0; r < 16; ++r) {
                float4 w = wv[wbase + (size_t)r * KQ_ + k4];
                acc[r] += a.x * w.x + a.y * w.y + a.z * w.z + a.w * w.w;
            }
        }

        // ---- wait for all h of step s-1 ----
        if (s) {
            const int tgt = (blockIdx.x & 128) ? 0 : 0;  // (no-op; keep uniform)
            const int want = 128 * s;
            while (__hip_atomic_load(cn, __ATOMIC_RELAXED,
                                     __HIP_MEMORY_SCOPE_AGENT) < want)
                __builtin_amdgcn_s_sleep(1);
            (void)tgt;
        }
        asm volatile("" ::: "memory");

        // ---- h-part: device-coherent loads from ping-pong buffer ----
        const float* __restrict__ hin = (s & 1) ? hb : ha;
        const int* __restrict__ hbi =
            (const int*)hin + (size_t)dir * HQ_ * B_ * 4 + (lane << 2);
        for (int k4 = k4h0; k4 < KQ_; k4 += 8) {
            const int kh = k4 - IQ_;
            const int* hp4 = hbi + ((size_t)kh * B_ << 2);
            int q0 = __hip_atomic_load(hp4 + 0, __ATOMIC_RELAXED, __HIP_MEMORY_SCOPE_AGENT);
            int q1 = __hip_atomic_load(hp4 + 1, __ATOMIC_RELAXED, __HIP_MEMORY_SCOPE_AGENT);
            int q2 = __hip_atomic_load(hp4 + 2, __ATOMIC_RELAXED, __HIP_MEMORY_SCOPE_AGENT);
            int q3 = __hip_atomic_load(hp4 + 3, __ATOMIC_RELAXED, __HIP_MEMORY_SCOPE_AGENT);
            float ax = __int_as_float(q0), ay = __int_as_float(q1);
            float az = __int_as_float(q2), aw = __int_as_float(q3);
#pragma unroll
            for (int r = 0; r < 16; ++r) {
                float4 w = wv[wbase + (size_t)r * KQ_ + k4];
                acc[r] += ax * w.x + ay * w.y + az * w.z + aw * w.w;
            }
        }

        // ---- combine partials ----
#pragma unroll
        for (int r = 0; r < 16; ++r) parts[(wq * 16 + r) * B_ + lane] = acc[r];
        __syncthreads();

        if (wq < 4) {
            float g0 = bi0, g1 = bi1, g2 = bi2, g3 = bi3;
#pragma unroll
            for (int w = 0; w < 8; ++w) {
                const float* pw = &parts[(w * 16 + wq * 4) * B_ + lane];
                g0 += pw[0 * B_]; g1 += pw[1 * B_];
                g2 += pw[2 * B_]; g3 += pw[3 * B_];
            }
            const bool valid = (s < Lb);
            float ii = 1.f / (1.f + expf(-g0));
            float ff = 1.f / (1.f + expf(-g1));
            float gg = tanhf(g2);
            float oo = 1.f / (1.f + expf(-g3));
            float cn2 = ff * c_reg + ii * gg;
            float hn = oo * tanhf(cn2);
            if (valid) { c_reg = cn2; h_reg = hn; }
            ybase[(((size_t)s * H_ + uF) << 6) + lane] = valid ? hn : 0.f;
            float* __restrict__ hout = (s & 1) ? ha : hb;
            int* hdst = (int*)hout +
                ((((size_t)dir * HQ_ + ug) * B_ + lane) << 2) + wq;
            __hip_atomic_store(hdst, __float_as_int(h_reg),
                               __ATOMIC_RELAXED, __HIP_MEMORY_SCOPE_AGENT);
        }

        // drain own stores, then block barrier (all waves' stores complete),
        // then one arrival RMW.
        asm volatile("s_waitcnt vmcnt(0)" ::: "memory");
        __syncthreads();
        if (tid == 0)
            __hip_atomic_fetch_add(cn, 1, __ATOMIC_RELAXED,
                                   __HIP_MEMORY_SCOPE_AGENT);
    }
}

// ---------------- logits / CRF epilogue ----------------
__global__ __launch_bounds__(256) void k_logits(const float* __restrict__ yf,
                                                const float* __restrict__ ybr,
                                                const float* __restrict__ wc,
                                                const float* __restrict__ bcv,
                                                float* __restrict__ L1,
                                                float* __restrict__ L2p) {
    __shared__ float smem[T_ * H_];
    int part = blockIdx.x >> 9;
    int s = blockIdx.x & 511;
    int tid = threadIdx.x;
    const float* y = part ? ybr : yf;
    float* Ldst = part ? L2p : L1;
    for (int idx = tid; idx < T_ * H_; idx += 256) {
        int t = idx >> 9;
        int h = idx & 511;
        smem[idx] = wc[(size_t)t * 1024 + part * 512 + h];
    }
    __syncthreads();
    int q = tid >> 6, b = tid & 63;
    float acc[T_];
#pragma unroll
    for (int t = 0; t < T_; ++t) acc[t] = 0.f;
    const float* yrow = y + (size_t)s * H_ * B_ + b;
    for (int h = q * 128; h < q * 128 + 128; ++h) {
        float a = yrow[(size_t)h * B_];
#pragma unroll
        for (int t = 0; t < T_; ++t) acc[t] += a * smem[t * H_ + h];
    }
    __syncthreads();
    float* pl = smem;
#pragma unroll
    for (int t = 0; t < T_; ++t) pl[(q * 64 + b) * 26 + t] = acc[t];
    __syncthreads();
    for (int idx = tid; idx < B_ * T_; idx += 256) {
        int bb2 = idx / T_;
        int t = idx - bb2 * T_;
        float v = pl[(0 * 64 + bb2) * 26 + t] + pl[(1 * 64 + bb2) * 26 + t] +
                  pl[(2 * 64 + bb2) * 26 + t] + pl[(3 * 64 + bb2) * 26 + t];
        if (!part) v += bcv[t];
        Ldst[((size_t)bb2 * S_ + s) * T_ + t] = v;
    }
}

__global__ void k_combine(const float* __restrict__ L1, const float* __restrict__ L2p,
                          const int* __restrict__ len, float* __restrict__ outlog) {
    int id = blockIdx.x * 256 + threadIdx.x;  // 32768 = B*S
    int b = id >> 9;
    int s = id & 511;
    int L = len[b];
    int sr = (s < L) ? (L - 1 - s) : s;
    const float* p1 = L1 + ((size_t)b * S_ + s) * T_;
    const float* p2 = L2p + ((size_t)b * S_ + sr) * T_;
    float* o = outlog + ((size_t)b * S_ + s) * T_;
#pragma unroll
    for (int t = 0; t < T_; ++t) o[t] = p1[t] + p2[t];
}

__global__ __launch_bounds__(64) void k_crf_nll(const float* __restrict__ em,
                                                const int* __restrict__ labels,
                                                const int* __restrict__ len,
                                                const float* __restrict__ cs,
                                                const float* __restrict__ ce,
                                                const float* __restrict__ ctr,
                                                float* __restrict__ llh) {
    int b = blockIdx.x, tid = threadIdx.x;
    __shared__ float tr[T_ * T_];
    __shared__ float sa[T_], sb[T_];
    for (int idx = tid; idx < T_ * T_; idx += 64) tr[idx] = ctr[idx];
    const float* e = em + (size_t)b * S_ * T_;
    int L = len[b];
    if (tid < T_) sa[tid] = cs[tid] + e[tid];
    __syncthreads();
    float* cur = sa;
    float* nx = sb;
    for (int t = 1; t < L; ++t) {
        if (tid < T_) {
            float m = -1e30f;
            for (int i = 0; i < T_; ++i) m = fmaxf(m, cur[i] + tr[i * T_ + tid]);
            float ssum = 0.f;
            for (int i = 0; i < T_; ++i) ssum += expf(cur[i] + tr[i * T_ + tid] - m);
            nx[tid] = m + logf(ssum) + e[(size_t)t * T_ + tid];
        }
        __syncthreads();
        float* tmp = cur; cur = nx; nx = tmp;
    }
    float part = 0.f;
    for (int t = tid; t < S_; t += 64) {
        if (t >= 1 && t < L) {
            int lp = labels[b * S_ + t - 1];
            int lc = labels[b * S_ + t];
            part += tr[lp * T_ + lc] + e[(size_t)t * T_ + lc];
        }
    }
    for (int off = 32; off; off >>= 1) part += __shfl_down(part, off, 64);
    if (tid == 0) {
        float m = -1e30f;
        for (int j = 0; j < T_; ++j) m = fmaxf(m, cur[j] + ce[j]);
        float ssum = 0.f;
        for (int j = 0; j < T_; ++j) ssum += expf(cur[j] + ce[j] - m);
        float denom = m + logf(ssum);
        int l0 = labels[b * S_];
        int lL = labels[b * S_ + L - 1];
        float num = cs[l0] + e[l0] + part + ce[lL];
        llh[b] = num - denom;
    }
}

__global__ void k_loss(const float* __restrict__ llh, const int* __restrict__ len,
                       float* __restrict__ out0) {
    int tid = threadIdx.x;
    float v = llh[tid];
    float n = (float)len[tid];
    for (int off = 32; off; off >>= 1) {
        v += __shfl_down(v, off, 64);
        n += __shfl_down(n, off, 64);
    }
    if (tid == 0) out0[0] = -(v / n);
}

__global__ __launch_bounds__(64) void k_viterbi(const float* __restrict__ em,
                                                const int* __restrict__ len,
                                                const float* __restrict__ cs,
                                                const float* __restrict__ ce,
                                                const float* __restrict__ ctr,
                                                float* __restrict__ otags,
                                                float* __restrict__ omask) {
    int b = blockIdx.x, tid = threadIdx.x;
    __shared__ float tr[T_ * T_];
    __shared__ float sa[T_], sb[T_];
    __shared__ unsigned char hist[(S_ - 1) * T_];
    __shared__ unsigned char tg[S_];
    for (int idx = tid; idx < T_ * T_; idx += 64) tr[idx] = ctr[idx];
    const float* e = em + (size_t)b * S_ * T_;
    int L = len[b];
    if (tid < T_) sa[tid] = cs[tid] + e[tid];
    __syncthreads();
    float* cur = sa;
    float* nx = sb;
    for (int t = 1; t < L; ++t) {
        if (tid < T_) {
            float best = -1e30f;
            int bi = 0;
            for (int i = 0; i < T_; ++i) {
                float v = cur[i] + tr[i * T_ + tid];
                if (v > best) { best = v; bi = i; }
            }
            nx[tid] = best + e[(size_t)t * T_ + tid];
            hist[(t - 1) * T_ + tid] = (unsigned char)bi;
        }
        __syncthreads();
        float* tmp = cur; cur = nx; nx = tmp;
    }
    if (tid == 0) {
        float best = -1e30f;
        int bt = 0;
        for (int j = 0; j < T_; ++j) {
            float v = cur[j] + ce[j];
            if (v > best) { best = v; bt = j; }
        }
        tg[S_ - 1] = (unsigned char)bt;
        for (int t = S_ - 2; t >= 0; --t) {
            if (t + 1 < L) bt = hist[t * T_ + bt];
            tg[t] = (unsigned char)bt;
        }
    }
    __syncthreads();
    for (int idx = tid; idx < S_; idx += 64) {
        otags[(size_t)b * S_ + idx] = (float)tg[idx];
        omask[(size_t)b * S_ + idx] = (idx < L) ? 1.f : 0.f;
    }
}

// ---------------- host launch ----------------
extern "C" void kernel_launch(void* const* d_in, const int* in_sizes, int n_in,
                              void* d_out, int out_size, void* d_ws, size_t ws_size,
                              hipStream_t stream) {
    const float* x    = (const float*)d_in[0];
    const float* wihf = (const float*)d_in[1];
    const float* whhf = (const float*)d_in[2];
    const float* bf   = (const float*)d_in[3];
    const float* wihb = (const float*)d_in[4];
    const float* whhb = (const float*)d_in[5];
    const float* bb   = (const float*)d_in[6];
    const float* wc   = (const float*)d_in[7];
    const float* bc   = (const float*)d_in[8];
    const float* cs   = (const float*)d_in[9];
    const float* ce   = (const float*)d_in[10];
    const float* ctr  = (const float*)d_in[11];
    const int* am     = (const int*)d_in[12];
    const int* labels = (const int*)d_in[13];

    float* ws   = (float*)d_ws;
    float* xt4  = ws + OFS_XT;
    float* xrt4 = ws + OFS_XRT;
    float* w4   = ws + OFS_WC;
    float* h4a  = ws + OFS_H0;
    float* h4b  = ws + OFS_H1;
    float* yf   = ws + OFS_YF;
    float* ybr  = ws + OFS_YB;
    float* L1p  = ws + OFS_L1;
    float* L2p  = ws + OFS_L2;
    int*   lenp = (int*)(ws + OFS_LEN);
    float* llhp = ws + OFS_LLH;
    int*   cntp = (int*)(ws + OFS_CNT);
    float* out  = (float*)d_out;

    k_lengths<<<1, 64, 0, stream>>>(am, lenp);
    k_prep_w4<<<2048, 256, 0, stream>>>(wihf, whhf, wihb, whhb, w4);
    k_zero<<<512, 256, 0, stream>>>(h4a, 2 * 2 * H_ * B_);  // h4a, h4b
    k_zero<<<1, 64, 0, stream>>>(ws + OFS_CNT, 64);          // counters
    k_xpose4<<<1024, 256, 0, stream>>>(x, lenp, xt4, xrt4);

    {
        void* kargs[] = {
            (void*)&w4, (void*)&xt4, (void*)&xrt4,
            (void*)&h4a, (void*)&h4b,
            (void*)&yf, (void*)&ybr,
            (void*)&bf, (void*)&bb,
            (void*)&lenp, (void*)&cntp
        };
        hipLaunchCooperativeKernel((const void*)k_scan,
                                   dim3(256), dim3(512), kargs, 0, stream);
    }

    k_logits<<<1024, 256, 0, stream>>>(yf, ybr, wc, bc, L1p, L2p);
    k_combine<<<128, 256, 0, stream>>>(L1p, L2p, lenp, out + OFF_LOGITS);
    k_crf_nll<<<64, 64, 0, stream>>>(out + OFF_LOGITS, labels, lenp, cs, ce, ctr, llhp);
    k_loss<<<1, 64, 0, stream>>>(llhp, lenp, out);
    k_viterbi<<<64, 64, 0, stream>>>(out + OFF_LOGITS, lenp, cs, ce, ctr,
                                     out + OFF_TAGS, out + OFF_MASK);
}